// Round 1
// baseline (2643.773 us; speedup 1.0000x reference)
//
#include <hip/hip_runtime.h>
#include <hip/hip_bf16.h>
#include <math.h>

// ---------------------------------------------------------------------------
// Problem constants: B=4, L_IN=1024, C_IN=7, C_MARK=4, D=512, H=8, DK=64,
// DFF=2048, NL=4, WINDOW=[4,4,4], INNER=5.  all_size=[1024,256,64,16], L=1360.
// ---------------------------------------------------------------------------

// ---------------- embed: circular conv3 + posenc + mark projection ---------
__global__ __launch_bounds__(512) void embed_kernel(
    const float* __restrict__ x_enc, const float* __restrict__ x_mark,
    const float* __restrict__ conv_w, const float* __restrict__ conv_b,
    const float* __restrict__ temp_w, const float* __restrict__ temp_b,
    float* __restrict__ e) {
  int bl = blockIdx.x;           // b*1024 + l
  int b = bl >> 10, l = bl & 1023;
  int d = threadIdx.x;
  int lm1 = (l + 1023) & 1023;
  int lp1 = (l + 1) & 1023;
  const float* w  = conv_w + d * 21;
  const float* x0 = x_enc + (size_t)(b * 1024 + lm1) * 7;
  const float* x1 = x_enc + (size_t)(b * 1024 + l)   * 7;
  const float* x2 = x_enc + (size_t)(b * 1024 + lp1) * 7;
  float acc = conv_b[d];
#pragma unroll
  for (int ci = 0; ci < 7; ci++) {
    acc = fmaf(x0[ci], w[ci * 3 + 0], acc);
    acc = fmaf(x1[ci], w[ci * 3 + 1], acc);
    acc = fmaf(x2[ci], w[ci * 3 + 2], acc);
  }
  // positional encoding: pe[l, 2j] = sin(l*div_j), pe[l, 2j+1] = cos(l*div_j)
  int j = d >> 1;
  float dv = expf((float)(2 * j) * (-9.210340371976184f / 512.0f));
  float ang = (float)l * dv;
  float pe = (d & 1) ? cosf(ang) : sinf(ang);
  const float* xm = x_mark + (size_t)(b * 1024 + l) * 4;
  float mk = temp_b[d];
  mk = fmaf(xm[0], temp_w[d],        mk);
  mk = fmaf(xm[1], temp_w[512 + d],  mk);
  mk = fmaf(xm[2], temp_w[1024 + d], mk);
  mk = fmaf(xm[3], temp_w[1536 + d], mk);
  e[(size_t)bl * 512 + d] = acc + pe + mk;
}

// ---------------- generic tiled f32 GEMM: C = act(A@B + bias) --------------
// Requires M%64==0, N%64==0, K%16==0 (all call sites satisfy this).
// act: 0 = none, 1 = exact GELU.
__global__ __launch_bounds__(256) void gemm_f32(
    const float* __restrict__ A, const float* __restrict__ B,
    const float* __restrict__ bias, float* __restrict__ C,
    int M, int N, int K, int act) {
  __shared__ float As[16][68];   // [k][m], padded: kills 16-way bank conflict
  __shared__ float Bs[16][64];   // [k][n]
  int tid = threadIdx.x;
  int tx = tid & 15, ty = tid >> 4;
  int bm = blockIdx.y << 6, bn = blockIdx.x << 6;
  const float* Ab = A + (size_t)bm * K;
  const float* Bb = B + bn;
  float acc[4][4] = {};
  for (int kt = 0; kt < K; kt += 16) {
#pragma unroll
    for (int r = 0; r < 4; r++) {
      int e2 = r * 256 + tid;
      int row = e2 >> 4, col = e2 & 15;
      As[col][row] = Ab[(size_t)row * K + kt + col];
    }
#pragma unroll
    for (int r = 0; r < 4; r++) {
      int e2 = r * 256 + tid;
      int row = e2 >> 6, col = e2 & 63;
      Bs[row][col] = Bb[(size_t)(kt + row) * N + col];
    }
    __syncthreads();
#pragma unroll
    for (int kk = 0; kk < 16; kk++) {
      float a0 = As[kk][(ty << 2) + 0], a1 = As[kk][(ty << 2) + 1];
      float a2 = As[kk][(ty << 2) + 2], a3 = As[kk][(ty << 2) + 3];
      float b0 = Bs[kk][(tx << 2) + 0], b1 = Bs[kk][(tx << 2) + 1];
      float b2 = Bs[kk][(tx << 2) + 2], b3 = Bs[kk][(tx << 2) + 3];
      acc[0][0] = fmaf(a0, b0, acc[0][0]); acc[0][1] = fmaf(a0, b1, acc[0][1]);
      acc[0][2] = fmaf(a0, b2, acc[0][2]); acc[0][3] = fmaf(a0, b3, acc[0][3]);
      acc[1][0] = fmaf(a1, b0, acc[1][0]); acc[1][1] = fmaf(a1, b1, acc[1][1]);
      acc[1][2] = fmaf(a1, b2, acc[1][2]); acc[1][3] = fmaf(a1, b3, acc[1][3]);
      acc[2][0] = fmaf(a2, b0, acc[2][0]); acc[2][1] = fmaf(a2, b1, acc[2][1]);
      acc[2][2] = fmaf(a2, b2, acc[2][2]); acc[2][3] = fmaf(a2, b3, acc[2][3]);
      acc[3][0] = fmaf(a3, b0, acc[3][0]); acc[3][1] = fmaf(a3, b1, acc[3][1]);
      acc[3][2] = fmaf(a3, b2, acc[3][2]); acc[3][3] = fmaf(a3, b3, acc[3][3]);
    }
    __syncthreads();
  }
#pragma unroll
  for (int i2 = 0; i2 < 4; i2++) {
    int row = bm + (ty << 2) + i2;
#pragma unroll
    for (int j2 = 0; j2 < 4; j2++) {
      int col = bn + (tx << 2) + j2;
      float v2 = acc[i2][j2] + (bias ? bias[col] : 0.0f);
      if (act == 1) v2 = 0.5f * v2 * (1.0f + erff(v2 * 0.7071067811865475f));
      C[(size_t)row * N + col] = v2;
    }
  }
}

// ---------------- pyramid conv level: stride-4 width-4 conv + affine + ELU --
__global__ __launch_bounds__(64) void pyr_conv(
    const float* __restrict__ in, int in_base, int in_bstr,
    float* __restrict__ out, int out_base, int out_bstr, int out_len,
    const float* __restrict__ w, const float* __restrict__ bias,
    const float* __restrict__ bng, const float* __restrict__ bnb) {
  int blk = blockIdx.x;
  int b = blk / out_len, to = blk - b * out_len;
  int co = threadIdx.x;
  __shared__ float xin[4][64];
  const float* src = in + (size_t)(b * in_bstr + in_base + 4 * to) * 64;
#pragma unroll
  for (int r2 = 0; r2 < 4; r2++) xin[r2][co] = src[r2 * 64 + co];
  __syncthreads();
  const float* wr = w + (size_t)co * 256;  // [co][ci][k]
  float acc = bias[co];
#pragma unroll 16
  for (int ci = 0; ci < 64; ci++) {
    acc = fmaf(xin[0][ci], wr[ci * 4 + 0], acc);
    acc = fmaf(xin[1][ci], wr[ci * 4 + 1], acc);
    acc = fmaf(xin[2][ci], wr[ci * 4 + 2], acc);
    acc = fmaf(xin[3][ci], wr[ci * 4 + 3], acc);
  }
  float y = fmaf(bng[co], acc, bnb[co]);
  y = y > 0.0f ? y : expm1f(y);
  out[(size_t)(b * out_bstr + out_base + to) * 64 + co] = y;
}

// ---------------- LayerNorm over concat([embed, pyr_up]) -------------------
__global__ __launch_bounds__(256) void ln_concat(
    const float* __restrict__ e, const float* __restrict__ pyru,
    const float* __restrict__ g, const float* __restrict__ bta,
    float* __restrict__ seq) {
  int r = blockIdx.x;
  int b = r / 1360, i = r - b * 1360;
  int tid = threadIdx.x;
  const float* src = (i < 1024)
      ? (e    + (size_t)(b * 1024 + i) * 512)
      : (pyru + (size_t)(b * 336 + (i - 1024)) * 512);
  float v0 = src[tid], v1 = src[tid + 256];
  __shared__ float red[256];
  red[tid] = v0 + v1;
  __syncthreads();
  for (int st = 128; st > 0; st >>= 1) { if (tid < st) red[tid] += red[tid + st]; __syncthreads(); }
  float mu = red[0] * (1.0f / 512.0f);
  __syncthreads();
  float d0 = v0 - mu, d1 = v1 - mu;
  red[tid] = d0 * d0 + d1 * d1;
  __syncthreads();
  for (int st = 128; st > 0; st >>= 1) { if (tid < st) red[tid] += red[tid + st]; __syncthreads(); }
  float inv = rsqrtf(red[0] * (1.0f / 512.0f) + 1e-5f);
  float* dst = seq + (size_t)r * 512;
  dst[tid]       = d0 * inv * g[tid]       + bta[tid];
  dst[tid + 256] = d1 * inv * g[tid + 256] + bta[tid + 256];
}

// ---------------- residual add + LayerNorm (in-place on seq) ---------------
__global__ __launch_bounds__(256) void ln_add(
    float* __restrict__ seq, const float* __restrict__ t1,
    const float* __restrict__ g, const float* __restrict__ bta) {
  int r = blockIdx.x;
  int tid = threadIdx.x;
  float* row = seq + (size_t)r * 512;
  const float* trow = t1 + (size_t)r * 512;
  float v0 = row[tid] + trow[tid];
  float v1 = row[tid + 256] + trow[tid + 256];
  __shared__ float red[256];
  red[tid] = v0 + v1;
  __syncthreads();
  for (int st = 128; st > 0; st >>= 1) { if (tid < st) red[tid] += red[tid + st]; __syncthreads(); }
  float mu = red[0] * (1.0f / 512.0f);
  __syncthreads();
  float d0 = v0 - mu, d1 = v1 - mu;
  red[tid] = d0 * d0 + d1 * d1;
  __syncthreads();
  for (int st = 128; st > 0; st >>= 1) { if (tid < st) red[tid] += red[tid + st]; __syncthreads(); }
  float inv = rsqrtf(red[0] * (1.0f / 512.0f) + 1e-5f);
  row[tid]       = d0 * inv * g[tid]       + bta[tid];
  row[tid + 256] = d1 * inv * g[tid + 256] + bta[tid + 256];
}

// ---------------- sparse pyramidal attention -------------------------------
// Mask structure: query i attends to <=10 keys: same-level |di|<=2 neighbors,
// 4 children (level li-1), 1 parent (level li+1). Masked entries are exact
// zeros after softmax (exp(-1e9 - m) underflows), so this is exact.
// Block = 512 threads = 8 waves; wave h handles head h of row (b,i).
__global__ __launch_bounds__(512) void attn_sparse(
    const float* __restrict__ q, const float* __restrict__ k,
    const float* __restrict__ v, float* __restrict__ o) {
  int r = blockIdx.x;
  int b = r / 1360, i = r - b * 1360;
  int h = threadIdx.x >> 6, lane = threadIdx.x & 63;
  __shared__ float sc[8][16];
  __shared__ int keys_s[16];
  __shared__ int nk_s;
  if (threadIdx.x == 0) {
    int S, sz, li;
    if (i < 1024)      { li = 0; S = 0;    sz = 1024; }
    else if (i < 1280) { li = 1; S = 1024; sz = 256; }
    else if (i < 1344) { li = 2; S = 1280; sz = 64; }
    else               { li = 3; S = 1344; sz = 16; }
    int p = i - S;
    int nk = 0;
    int lo = p - 2; if (lo < 0) lo = 0;
    int hi = p + 2; if (hi > sz - 1) hi = sz - 1;
    for (int j2 = lo; j2 <= hi; j2++) keys_s[nk++] = S + j2;
    if (li > 0) {
      int Sprev = (li == 1) ? 0 : (li == 2) ? 1024 : 1280;
      int cb = Sprev + 4 * p;
      keys_s[nk++] = cb; keys_s[nk++] = cb + 1;
      keys_s[nk++] = cb + 2; keys_s[nk++] = cb + 3;
    }
    if (li < 3) {
      int Snext = (li == 0) ? 1024 : (li == 1) ? 1280 : 1344;
      keys_s[nk++] = Snext + (p >> 2);
    }
    nk_s = nk;
  }
  __syncthreads();
  int nk = nk_s;
  const float* qrow = q + (size_t)r * 512 + h * 64;
  if (lane < nk) {
    const float* krow = k + (size_t)(b * 1360 + keys_s[lane]) * 512 + h * 64;
    float s = 0.0f;
#pragma unroll
    for (int d2 = 0; d2 < 64; d2++) s = fmaf(qrow[d2], krow[d2], s);
    sc[h][lane] = s * 0.125f;  // q / sqrt(DK)
  }
  __syncthreads();
  float m = -1e30f;
  for (int j2 = 0; j2 < nk; j2++) m = fmaxf(m, sc[h][j2]);
  float denom = 0.0f;
  for (int j2 = 0; j2 < nk; j2++) denom += expf(sc[h][j2] - m);
  float inv = 1.0f / denom;
  float acc = 0.0f;
  for (int j2 = 0; j2 < nk; j2++) {
    float pj = expf(sc[h][j2] - m) * inv;
    acc = fmaf(pj, v[(size_t)(b * 1360 + keys_s[j2]) * 512 + h * 64 + lane], acc);
  }
  o[(size_t)r * 512 + h * 64 + lane] = acc;
}

// ---------------- output gather: seq[:, idx, :] ----------------------------
__global__ __launch_bounds__(512) void gather_out(
    const float* __restrict__ seq, float* __restrict__ out) {
  int bl = blockIdx.x;          // b*1024 + i
  int b = bl >> 10, i = bl & 1023;
  int d = threadIdx.x;
  size_t ob = (size_t)bl * 2048 + d;
  size_t base = (size_t)b * 1360;
  out[ob]        = seq[(base + i) * 512 + d];
  out[ob + 512]  = seq[(base + 1024 + (i >> 2)) * 512 + d];
  out[ob + 1024] = seq[(base + 1280 + (i >> 4)) * 512 + d];
  out[ob + 1536] = seq[(base + 1344 + (i >> 6)) * 512 + d];
}

// ---------------------------------------------------------------------------
extern "C" void kernel_launch(void* const* d_in, const int* in_sizes, int n_in,
                              void* d_out, int out_size, void* d_ws, size_t ws_size,
                              hipStream_t stream) {
  const float* x_enc   = (const float*)d_in[0];
  const float* x_mark  = (const float*)d_in[1];
  const float* conv_w  = (const float*)d_in[2];
  const float* conv_b  = (const float*)d_in[3];
  const float* temp_w  = (const float*)d_in[4];
  const float* temp_b  = (const float*)d_in[5];
  const float* down_w  = (const float*)d_in[6];
  const float* down_b  = (const float*)d_in[7];
  const float* pyr_w   = (const float*)d_in[8];
  const float* pyr_b   = (const float*)d_in[9];
  const float* bn_g    = (const float*)d_in[10];
  const float* bn_b    = (const float*)d_in[11];
  const float* up_w    = (const float*)d_in[12];
  const float* up_b    = (const float*)d_in[13];
  const float* norm_g  = (const float*)d_in[14];
  const float* norm_b  = (const float*)d_in[15];
  const float* wq      = (const float*)d_in[16];
  const float* wk      = (const float*)d_in[17];
  const float* wv      = (const float*)d_in[18];
  const float* fc_w    = (const float*)d_in[19];
  const float* fc_b    = (const float*)d_in[20];
  const float* ln1_g   = (const float*)d_in[21];
  const float* ln1_b   = (const float*)d_in[22];
  const float* w1      = (const float*)d_in[23];
  const float* b1      = (const float*)d_in[24];
  const float* w2      = (const float*)d_in[25];
  const float* b2      = (const float*)d_in[26];
  const float* ln2_g   = (const float*)d_in[27];
  const float* ln2_b   = (const float*)d_in[28];

  // workspace layout (floats). th aliases q..o (FFN hidden vs attention bufs).
  float* ws   = (float*)d_ws;
  float* e    = ws;                    // 4*1024*512   = 2,097,152
  float* tmp0 = e    + 2097152;        // 4*1024*64    =   262,144
  float* pyrf = tmp0 + 262144;         // 4*336*64     =    86,016
  float* pyru = pyrf + 86016;          // 4*336*512    =   688,128
  float* seq  = pyru + 688128;         // 4*1360*512   = 2,785,280
  float* q    = seq  + 2785280;        // 2,785,280
  float* kb   = q    + 2785280;        // 2,785,280
  float* vb   = kb   + 2785280;        // 2,785,280
  float* o    = vb   + 2785280;        // 2,785,280
  float* t1   = o    + 2785280;        // 2,785,280
  float* th   = q;                     // 4*1360*2048 = 11,141,120 (alias q..o)

  embed_kernel<<<4096, 512, 0, stream>>>(x_enc, x_mark, conv_w, conv_b,
                                         temp_w, temp_b, e);
  // down: (4096,512)@(512,64)
  gemm_f32<<<dim3(1, 64), 256, 0, stream>>>(e, down_w, down_b, tmp0,
                                            4096, 64, 512, 0);
  // pyramid levels (1024->256->64->16), concatenated into pyrf rows [0,336)
  pyr_conv<<<4 * 256, 64, 0, stream>>>(tmp0, 0, 1024, pyrf, 0, 336, 256,
                                       pyr_w, pyr_b, bn_g, bn_b);
  pyr_conv<<<4 * 64, 64, 0, stream>>>(pyrf, 0, 336, pyrf, 256, 336, 64,
                                      pyr_w + 16384, pyr_b + 64, bn_g + 64, bn_b + 64);
  pyr_conv<<<4 * 16, 64, 0, stream>>>(pyrf, 256, 336, pyrf, 320, 336, 16,
                                      pyr_w + 32768, pyr_b + 128, bn_g + 128, bn_b + 128);
  // up: (1344,64)@(64,512)
  gemm_f32<<<dim3(8, 21), 256, 0, stream>>>(pyrf, up_w, up_b, pyru,
                                            1344, 512, 64, 0);
  ln_concat<<<5440, 256, 0, stream>>>(e, pyru, norm_g, norm_b, seq);

  for (int l = 0; l < 4; l++) {
    const float* wql = wq + (size_t)l * 262144;
    const float* wkl = wk + (size_t)l * 262144;
    const float* wvl = wv + (size_t)l * 262144;
    gemm_f32<<<dim3(8, 85), 256, 0, stream>>>(seq, wql, nullptr, q,  5440, 512, 512, 0);
    gemm_f32<<<dim3(8, 85), 256, 0, stream>>>(seq, wkl, nullptr, kb, 5440, 512, 512, 0);
    gemm_f32<<<dim3(8, 85), 256, 0, stream>>>(seq, wvl, nullptr, vb, 5440, 512, 512, 0);
    attn_sparse<<<5440, 512, 0, stream>>>(q, kb, vb, o);
    gemm_f32<<<dim3(8, 85), 256, 0, stream>>>(o, fc_w + (size_t)l * 262144,
                                              fc_b + l * 512, t1, 5440, 512, 512, 0);
    ln_add<<<5440, 256, 0, stream>>>(seq, t1, ln1_g + l * 512, ln1_b + l * 512);
    gemm_f32<<<dim3(32, 85), 256, 0, stream>>>(seq, w1 + (size_t)l * 1048576,
                                               b1 + l * 2048, th, 5440, 2048, 512, 1);
    gemm_f32<<<dim3(8, 85), 256, 0, stream>>>(th, w2 + (size_t)l * 1048576,
                                              b2 + l * 512, t1, 5440, 512, 2048, 0);
    ln_add<<<5440, 256, 0, stream>>>(seq, t1, ln2_g + l * 512, ln2_b + l * 512);
  }
  gather_out<<<4096, 512, 0, stream>>>(seq, (float*)d_out);
}

// Round 2
// 859.735 us; speedup vs baseline: 3.0751x; 3.0751x over previous
//
#include <hip/hip_runtime.h>
#include <hip/hip_bf16.h>
#include <math.h>

// ---------------------------------------------------------------------------
// B=4, L_IN=1024, D=512, H=8, DK=64, DFF=2048, NL=4, WINDOW=[4,4,4], INNER=5.
// all_size=[1024,256,64,16], L_tot=1360, rows M=5440 padded to M_PAD=5504.
// ---------------------------------------------------------------------------

typedef __attribute__((ext_vector_type(8))) short short8;
typedef __attribute__((ext_vector_type(4))) float f32x4;

__device__ inline ushort f2bf(float x) {
  union { __hip_bfloat16 h; ushort u; } cv; cv.h = __float2bfloat16(x); return cv.u;
}
__device__ inline float bf2f(ushort u) {
  union { unsigned int i; float f; } cv; cv.i = (unsigned)u << 16; return cv.f;
}
__device__ inline float lo16(unsigned u) { union { unsigned i; float f; } c; c.i = u << 16; return c.f; }
__device__ inline float hi16(unsigned u) { union { unsigned i; float f; } c; c.i = u & 0xffff0000u; return c.f; }

#define GLD16(gp, lp)                                                        \
  __builtin_amdgcn_global_load_lds(                                          \
      (const __attribute__((address_space(1))) void*)(gp),                   \
      (__attribute__((address_space(3))) void*)(lp), 16, 0, 0)

// ---------------- embed: circular conv3 + posenc + mark projection ---------
__global__ __launch_bounds__(512) void embed_kernel(
    const float* __restrict__ x_enc, const float* __restrict__ x_mark,
    const float* __restrict__ conv_w, const float* __restrict__ conv_b,
    const float* __restrict__ temp_w, const float* __restrict__ temp_b,
    float* __restrict__ e) {
  int bl = blockIdx.x;
  int b = bl >> 10, l = bl & 1023;
  int d = threadIdx.x;
  int lm1 = (l + 1023) & 1023;
  int lp1 = (l + 1) & 1023;
  const float* w  = conv_w + d * 21;
  const float* x0 = x_enc + (size_t)(b * 1024 + lm1) * 7;
  const float* x1 = x_enc + (size_t)(b * 1024 + l)   * 7;
  const float* x2 = x_enc + (size_t)(b * 1024 + lp1) * 7;
  float acc = conv_b[d];
#pragma unroll
  for (int ci = 0; ci < 7; ci++) {
    acc = fmaf(x0[ci], w[ci * 3 + 0], acc);
    acc = fmaf(x1[ci], w[ci * 3 + 1], acc);
    acc = fmaf(x2[ci], w[ci * 3 + 2], acc);
  }
  int j = d >> 1;
  float dv = expf((float)(2 * j) * (-9.210340371976184f / 512.0f));
  float ang = (float)l * dv;
  float pe = (d & 1) ? cosf(ang) : sinf(ang);
  const float* xm = x_mark + (size_t)(b * 1024 + l) * 4;
  float mk = temp_b[d];
  mk = fmaf(xm[0], temp_w[d],        mk);
  mk = fmaf(xm[1], temp_w[512 + d],  mk);
  mk = fmaf(xm[2], temp_w[1024 + d], mk);
  mk = fmaf(xm[3], temp_w[1536 + d], mk);
  e[(size_t)bl * 512 + d] = acc + pe + mk;
}

// ---------------- weight cast+transpose: f32 [K][N] -> bf16 [N][K] ---------
__global__ __launch_bounds__(256) void transpose_cast(
    const float* __restrict__ src, ushort* __restrict__ dst,
    int K, int N, size_t src_lstride, size_t dst_lstride) {
  src += (size_t)blockIdx.z * src_lstride;
  dst += (size_t)blockIdx.z * dst_lstride;
  __shared__ float t[32][33];
  int k0 = blockIdx.y * 32, n0 = blockIdx.x * 32;
  int tx = threadIdx.x, ty = threadIdx.y;  // (32,8)
#pragma unroll
  for (int i = 0; i < 4; i++)
    t[ty + i * 8][tx] = src[(size_t)(k0 + ty + i * 8) * N + n0 + tx];
  __syncthreads();
#pragma unroll
  for (int i = 0; i < 4; i++)
    dst[(size_t)(n0 + ty + i * 8) * K + k0 + tx] = f2bf(t[tx][ty + i * 8]);
}

// ---------------- bf16 MFMA GEMM (m97 structure): C = act(A@B^T + bias) ----
// A: [M_pad][K] bf16 row-major.  Bt: [N][K] bf16 row-major (pre-transposed).
// 128x128 tile, 4 waves, BK=32, 16x16x32 MFMA, global_load_lds width 16.
// M_pad%128==0, N%128==0, K%32==0. act: 1 = exact GELU. out_bf16: C is bf16.
__global__ __launch_bounds__(256) void gemm_bf16(
    const ushort* __restrict__ A, const ushort* __restrict__ Bt,
    const float* __restrict__ bias, void* __restrict__ C,
    int N, int K, int act, int out_bf16) {
  __shared__ short As[4096];   // 128 x 32
  __shared__ short Bs[4096];
  int tid = threadIdx.x;
  int w = tid >> 6, lane = tid & 63;
  int bm = blockIdx.y << 7, bn = blockIdx.x << 7;
  const short* Ab = (const short*)A + (size_t)(bm + (tid >> 2)) * K + (tid & 3) * 8;
  const short* Bb = (const short*)Bt + (size_t)(bn + (tid >> 2)) * K + (tid & 3) * 8;
  int ldsw = (tid & 192) * 8;          // wave-uniform: w*512 shorts
  int wr = (w >> 1) << 6, wc = (w & 1) << 6;
  int lr = lane & 15, kg = lane >> 4;
  f32x4 acc[4][4] = {};
  for (int kt = 0; kt < K; kt += 32) {
    GLD16(Ab + kt,                    &As[ldsw]);
    GLD16(Ab + kt + (size_t)64 * K,   &As[2048 + ldsw]);
    GLD16(Bb + kt,                    &Bs[ldsw]);
    GLD16(Bb + kt + (size_t)64 * K,   &Bs[2048 + ldsw]);
    __syncthreads();
    short8 a_[4], b_[4];
#pragma unroll
    for (int m = 0; m < 4; m++)
      a_[m] = *(const short8*)&As[(wr + m * 16 + lr) * 32 + kg * 8];
#pragma unroll
    for (int n = 0; n < 4; n++)
      b_[n] = *(const short8*)&Bs[(wc + n * 16 + lr) * 32 + kg * 8];
#pragma unroll
    for (int m = 0; m < 4; m++)
#pragma unroll
      for (int n = 0; n < 4; n++)
        acc[m][n] = __builtin_amdgcn_mfma_f32_16x16x32_bf16(a_[m], b_[n], acc[m][n], 0, 0, 0);
    __syncthreads();
  }
  int r0 = bm + wr + kg * 4;
  int c0 = bn + wc + lr;
#pragma unroll
  for (int m = 0; m < 4; m++) {
#pragma unroll
    for (int n = 0; n < 4; n++) {
      int col = c0 + n * 16;
      float bv = bias ? bias[col] : 0.0f;
#pragma unroll
      for (int j = 0; j < 4; j++) {
        int row = r0 + m * 16 + j;
        float v = acc[m][n][j] + bv;
        if (act == 1) v = 0.5f * v * (1.0f + erff(v * 0.7071067811865475f));
        if (out_bf16) ((ushort*)C)[(size_t)row * N + col] = f2bf(v);
        else          ((float*)C)[(size_t)row * N + col] = v;
      }
    }
  }
}

// ---------------- small f32 GEMM (down / up projections) -------------------
__global__ __launch_bounds__(256) void gemm_f32(
    const float* __restrict__ A, const float* __restrict__ B,
    const float* __restrict__ bias, float* __restrict__ C,
    int M, int N, int K) {
  __shared__ float As[16][68];
  __shared__ float Bs[16][64];
  int tid = threadIdx.x;
  int tx = tid & 15, ty = tid >> 4;
  int bm = blockIdx.y << 6, bn = blockIdx.x << 6;
  const float* Ab = A + (size_t)bm * K;
  const float* Bb = B + bn;
  float acc[4][4] = {};
  for (int kt = 0; kt < K; kt += 16) {
#pragma unroll
    for (int r = 0; r < 4; r++) {
      int e2 = r * 256 + tid;
      As[e2 & 15][e2 >> 4] = Ab[(size_t)(e2 >> 4) * K + kt + (e2 & 15)];
    }
#pragma unroll
    for (int r = 0; r < 4; r++) {
      int e2 = r * 256 + tid;
      Bs[e2 >> 6][e2 & 63] = Bb[(size_t)(kt + (e2 >> 6)) * N + (e2 & 63)];
    }
    __syncthreads();
#pragma unroll
    for (int kk = 0; kk < 16; kk++) {
      float a0 = As[kk][(ty << 2) + 0], a1 = As[kk][(ty << 2) + 1];
      float a2 = As[kk][(ty << 2) + 2], a3 = As[kk][(ty << 2) + 3];
      float b0 = Bs[kk][(tx << 2) + 0], b1 = Bs[kk][(tx << 2) + 1];
      float b2 = Bs[kk][(tx << 2) + 2], b3 = Bs[kk][(tx << 2) + 3];
      acc[0][0] = fmaf(a0, b0, acc[0][0]); acc[0][1] = fmaf(a0, b1, acc[0][1]);
      acc[0][2] = fmaf(a0, b2, acc[0][2]); acc[0][3] = fmaf(a0, b3, acc[0][3]);
      acc[1][0] = fmaf(a1, b0, acc[1][0]); acc[1][1] = fmaf(a1, b1, acc[1][1]);
      acc[1][2] = fmaf(a1, b2, acc[1][2]); acc[1][3] = fmaf(a1, b3, acc[1][3]);
      acc[2][0] = fmaf(a2, b0, acc[2][0]); acc[2][1] = fmaf(a2, b1, acc[2][1]);
      acc[2][2] = fmaf(a2, b2, acc[2][2]); acc[2][3] = fmaf(a2, b3, acc[2][3]);
      acc[3][0] = fmaf(a3, b0, acc[3][0]); acc[3][1] = fmaf(a3, b1, acc[3][1]);
      acc[3][2] = fmaf(a3, b2, acc[3][2]); acc[3][3] = fmaf(a3, b3, acc[3][3]);
    }
    __syncthreads();
  }
#pragma unroll
  for (int i2 = 0; i2 < 4; i2++) {
    int row = bm + (ty << 2) + i2;
#pragma unroll
    for (int j2 = 0; j2 < 4; j2++) {
      int col = bn + (tx << 2) + j2;
      C[(size_t)row * N + col] = acc[i2][j2] + (bias ? bias[col] : 0.0f);
    }
  }
}

// ---------------- pyramid conv level ---------------------------------------
__global__ __launch_bounds__(64) void pyr_conv(
    const float* __restrict__ in, int in_base, int in_bstr,
    float* __restrict__ out, int out_base, int out_bstr, int out_len,
    const float* __restrict__ w, const float* __restrict__ bias,
    const float* __restrict__ bng, const float* __restrict__ bnb) {
  int blk = blockIdx.x;
  int b = blk / out_len, to = blk - b * out_len;
  int co = threadIdx.x;
  __shared__ float xin[4][64];
  const float* src = in + (size_t)(b * in_bstr + in_base + 4 * to) * 64;
#pragma unroll
  for (int r2 = 0; r2 < 4; r2++) xin[r2][co] = src[r2 * 64 + co];
  __syncthreads();
  const float* wr = w + (size_t)co * 256;
  float acc = bias[co];
#pragma unroll 16
  for (int ci = 0; ci < 64; ci++) {
    acc = fmaf(xin[0][ci], wr[ci * 4 + 0], acc);
    acc = fmaf(xin[1][ci], wr[ci * 4 + 1], acc);
    acc = fmaf(xin[2][ci], wr[ci * 4 + 2], acc);
    acc = fmaf(xin[3][ci], wr[ci * 4 + 3], acc);
  }
  float y = fmaf(bng[co], acc, bnb[co]);
  y = y > 0.0f ? y : expm1f(y);
  out[(size_t)(b * out_bstr + out_base + to) * 64 + co] = y;
}

// ---------------- LayerNorm over concat([embed, pyr_up]); dual output ------
__global__ __launch_bounds__(256) void ln_concat(
    const float* __restrict__ e, const float* __restrict__ pyru,
    const float* __restrict__ g, const float* __restrict__ bta,
    float* __restrict__ seq, ushort* __restrict__ seq_bf) {
  int r = blockIdx.x;
  int b = r / 1360, i = r - b * 1360;
  int tid = threadIdx.x;
  const float* src = (i < 1024)
      ? (e    + (size_t)(b * 1024 + i) * 512)
      : (pyru + (size_t)(b * 336 + (i - 1024)) * 512);
  float v0 = src[tid], v1 = src[tid + 256];
  __shared__ float red[256];
  red[tid] = v0 + v1;
  __syncthreads();
  for (int st = 128; st > 0; st >>= 1) { if (tid < st) red[tid] += red[tid + st]; __syncthreads(); }
  float mu = red[0] * (1.0f / 512.0f);
  __syncthreads();
  float d0 = v0 - mu, d1 = v1 - mu;
  red[tid] = d0 * d0 + d1 * d1;
  __syncthreads();
  for (int st = 128; st > 0; st >>= 1) { if (tid < st) red[tid] += red[tid + st]; __syncthreads(); }
  float inv = rsqrtf(red[0] * (1.0f / 512.0f) + 1e-5f);
  float o0 = d0 * inv * g[tid]       + bta[tid];
  float o1 = d1 * inv * g[tid + 256] + bta[tid + 256];
  float* dst = seq + (size_t)r * 512;
  dst[tid] = o0; dst[tid + 256] = o1;
  ushort* dbf = seq_bf + (size_t)r * 512;
  dbf[tid] = f2bf(o0); dbf[tid + 256] = f2bf(o1);
}

// ---------------- residual add + LayerNorm (in-place), dual output ---------
__global__ __launch_bounds__(256) void ln_add(
    float* __restrict__ seq, const float* __restrict__ t1,
    const float* __restrict__ g, const float* __restrict__ bta,
    ushort* __restrict__ seq_bf) {
  int r = blockIdx.x;
  int tid = threadIdx.x;
  float* row = seq + (size_t)r * 512;
  const float* trow = t1 + (size_t)r * 512;
  float v0 = row[tid] + trow[tid];
  float v1 = row[tid + 256] + trow[tid + 256];
  __shared__ float red[256];
  red[tid] = v0 + v1;
  __syncthreads();
  for (int st = 128; st > 0; st >>= 1) { if (tid < st) red[tid] += red[tid + st]; __syncthreads(); }
  float mu = red[0] * (1.0f / 512.0f);
  __syncthreads();
  float d0 = v0 - mu, d1 = v1 - mu;
  red[tid] = d0 * d0 + d1 * d1;
  __syncthreads();
  for (int st = 128; st > 0; st >>= 1) { if (tid < st) red[tid] += red[tid + st]; __syncthreads(); }
  float inv = rsqrtf(red[0] * (1.0f / 512.0f) + 1e-5f);
  float o0 = d0 * inv * g[tid]       + bta[tid];
  float o1 = d1 * inv * g[tid + 256] + bta[tid + 256];
  row[tid] = o0; row[tid + 256] = o1;
  ushort* dbf = seq_bf + (size_t)r * 512;
  dbf[tid] = f2bf(o0); dbf[tid + 256] = f2bf(o1);
}

// ---------------- sparse pyramidal attention (bf16 qkv in, bf16 o out) -----
// Query i attends to <=10 keys (exact: masked terms are exact softmax zeros).
__global__ __launch_bounds__(512) void attn_sparse(
    const ushort* __restrict__ qkv, ushort* __restrict__ o) {
  int r = blockIdx.x;
  int b = r / 1360, i = r - b * 1360;
  int h = threadIdx.x >> 6, lane = threadIdx.x & 63;
  __shared__ float sc[8][16];
  __shared__ int keys_s[16];
  __shared__ int nk_s;
  if (threadIdx.x == 0) {
    int S, sz, li;
    if (i < 1024)      { li = 0; S = 0;    sz = 1024; }
    else if (i < 1280) { li = 1; S = 1024; sz = 256; }
    else if (i < 1344) { li = 2; S = 1280; sz = 64; }
    else               { li = 3; S = 1344; sz = 16; }
    int p = i - S;
    int nk = 0;
    int lo = p - 2; if (lo < 0) lo = 0;
    int hi = p + 2; if (hi > sz - 1) hi = sz - 1;
    for (int j2 = lo; j2 <= hi; j2++) keys_s[nk++] = S + j2;
    if (li > 0) {
      int Sprev = (li == 1) ? 0 : (li == 2) ? 1024 : 1280;
      int cb = Sprev + 4 * p;
      keys_s[nk++] = cb; keys_s[nk++] = cb + 1;
      keys_s[nk++] = cb + 2; keys_s[nk++] = cb + 3;
    }
    if (li < 3) {
      int Snext = (li == 0) ? 1024 : (li == 1) ? 1280 : 1344;
      keys_s[nk++] = Snext + (p >> 2);
    }
    nk_s = nk;
  }
  __syncthreads();
  int nk = nk_s;
  if (lane < nk) {
    const uint4* qv = (const uint4*)(qkv + (size_t)r * 1536 + h * 64);
    const uint4* kv = (const uint4*)(qkv + (size_t)(b * 1360 + keys_s[lane]) * 1536 + 512 + h * 64);
    float s = 0.0f;
#pragma unroll
    for (int c = 0; c < 8; c++) {
      uint4 a = qv[c], k4 = kv[c];
      s = fmaf(lo16(a.x), lo16(k4.x), s); s = fmaf(hi16(a.x), hi16(k4.x), s);
      s = fmaf(lo16(a.y), lo16(k4.y), s); s = fmaf(hi16(a.y), hi16(k4.y), s);
      s = fmaf(lo16(a.z), lo16(k4.z), s); s = fmaf(hi16(a.z), hi16(k4.z), s);
      s = fmaf(lo16(a.w), lo16(k4.w), s); s = fmaf(hi16(a.w), hi16(k4.w), s);
    }
    sc[h][lane] = s * 0.125f;
  }
  __syncthreads();
  float m = -1e30f;
  for (int j2 = 0; j2 < nk; j2++) m = fmaxf(m, sc[h][j2]);
  float denom = 0.0f;
  for (int j2 = 0; j2 < nk; j2++) denom += expf(sc[h][j2] - m);
  float inv = 1.0f / denom;
  float acc = 0.0f;
  for (int j2 = 0; j2 < nk; j2++) {
    float pj = expf(sc[h][j2] - m) * inv;
    float vv = bf2f(qkv[(size_t)(b * 1360 + keys_s[j2]) * 1536 + 1024 + h * 64 + lane]);
    acc = fmaf(pj, vv, acc);
  }
  o[(size_t)r * 512 + h * 64 + lane] = f2bf(acc);
}

// ---------------- output gather --------------------------------------------
__global__ __launch_bounds__(512) void gather_out(
    const float* __restrict__ seq, float* __restrict__ out) {
  int bl = blockIdx.x;
  int b = bl >> 10, i = bl & 1023;
  int d = threadIdx.x;
  size_t ob = (size_t)bl * 2048 + d;
  size_t base = (size_t)b * 1360;
  out[ob]        = seq[(base + i) * 512 + d];
  out[ob + 512]  = seq[(base + 1024 + (i >> 2)) * 512 + d];
  out[ob + 1024] = seq[(base + 1280 + (i >> 4)) * 512 + d];
  out[ob + 1536] = seq[(base + 1344 + (i >> 6)) * 512 + d];
}

// ---------------------------------------------------------------------------
extern "C" void kernel_launch(void* const* d_in, const int* in_sizes, int n_in,
                              void* d_out, int out_size, void* d_ws, size_t ws_size,
                              hipStream_t stream) {
  const float* x_enc   = (const float*)d_in[0];
  const float* x_mark  = (const float*)d_in[1];
  const float* conv_w  = (const float*)d_in[2];
  const float* conv_b  = (const float*)d_in[3];
  const float* temp_w  = (const float*)d_in[4];
  const float* temp_b  = (const float*)d_in[5];
  const float* down_w  = (const float*)d_in[6];
  const float* down_b  = (const float*)d_in[7];
  const float* pyr_w   = (const float*)d_in[8];
  const float* pyr_b   = (const float*)d_in[9];
  const float* bn_g    = (const float*)d_in[10];
  const float* bn_b    = (const float*)d_in[11];
  const float* up_w    = (const float*)d_in[12];
  const float* up_b    = (const float*)d_in[13];
  const float* norm_g  = (const float*)d_in[14];
  const float* norm_b  = (const float*)d_in[15];
  const float* wq      = (const float*)d_in[16];
  const float* wk      = (const float*)d_in[17];
  const float* wv      = (const float*)d_in[18];
  const float* fc_w    = (const float*)d_in[19];
  const float* fc_b    = (const float*)d_in[20];
  const float* ln1_g   = (const float*)d_in[21];
  const float* ln1_b   = (const float*)d_in[22];
  const float* w1      = (const float*)d_in[23];
  const float* b1      = (const float*)d_in[24];
  const float* w2      = (const float*)d_in[25];
  const float* b2      = (const float*)d_in[26];
  const float* ln2_g   = (const float*)d_in[27];
  const float* ln2_b   = (const float*)d_in[28];

  // ---- workspace layout (f32-word offsets); total 18,972,672 words = 72.4MB
  float* ws = (float*)d_ws;
  // region X [0 .. 5,636,096): prologue e/tmp0/pyrf/pyru, then per-layer
  //   qkv_bf (4,227,072 w) + o_bf (1,409,024 w), then th_bf (5,636,096 w).
  float*  e      = ws;                         // 2,097,152 w
  float*  tmp0   = ws + 2097152;               //   262,144 w
  float*  pyrf   = ws + 2359296;               //    86,016 w
  float*  pyru   = ws + 2445312;               //   688,128 w
  ushort* qkv_bf = (ushort*)ws;                // [5504][1536] bf16
  ushort* o_bf   = (ushort*)(ws + 4227072);    // [5504][512] bf16
  ushort* th_bf  = (ushort*)ws;                // [5504][2048] bf16
  float*  t1     = ws + 5636096;               // 2,818,048 w  [5504][512] f32
  float*  seq    = ws + 8454144;               // 2,818,048 w  [5504][512] f32
  ushort* seq_bf = (ushort*)(ws + 11272192);   // [5504][512] bf16
  ushort* qkvw   = (ushort*)(ws + 12681216);   // 4 x [1536][512] bf16
  ushort* fcw    = (ushort*)(ws + 14254080);   // 4 x [512][512] bf16
  ushort* w1t    = (ushort*)(ws + 14778368);   // 4 x [2048][512] bf16
  ushort* w2t    = (ushort*)(ws + 16875520);   // 4 x [512][2048] bf16

  // ---- weight cast+transpose (once per call) ----
  dim3 tb(32, 8);
  transpose_cast<<<dim3(16, 16, 4), tb, 0, stream>>>(wq, qkvw,          512, 512,  262144, 786432);
  transpose_cast<<<dim3(16, 16, 4), tb, 0, stream>>>(wk, qkvw + 262144, 512, 512,  262144, 786432);
  transpose_cast<<<dim3(16, 16, 4), tb, 0, stream>>>(wv, qkvw + 524288, 512, 512,  262144, 786432);
  transpose_cast<<<dim3(16, 16, 4), tb, 0, stream>>>(fc_w, fcw,         512, 512,  262144, 262144);
  transpose_cast<<<dim3(64, 16, 4), tb, 0, stream>>>(w1, w1t,           512, 2048, 1048576, 1048576);
  transpose_cast<<<dim3(16, 64, 4), tb, 0, stream>>>(w2, w2t,           2048, 512, 1048576, 1048576);

  // ---- prologue ----
  embed_kernel<<<4096, 512, 0, stream>>>(x_enc, x_mark, conv_w, conv_b,
                                         temp_w, temp_b, e);
  gemm_f32<<<dim3(1, 64), 256, 0, stream>>>(e, down_w, down_b, tmp0, 4096, 64, 512);
  pyr_conv<<<4 * 256, 64, 0, stream>>>(tmp0, 0, 1024, pyrf, 0, 336, 256,
                                       pyr_w, pyr_b, bn_g, bn_b);
  pyr_conv<<<4 * 64, 64, 0, stream>>>(pyrf, 0, 336, pyrf, 256, 336, 64,
                                      pyr_w + 16384, pyr_b + 64, bn_g + 64, bn_b + 64);
  pyr_conv<<<4 * 16, 64, 0, stream>>>(pyrf, 256, 336, pyrf, 320, 336, 16,
                                      pyr_w + 32768, pyr_b + 128, bn_g + 128, bn_b + 128);
  gemm_f32<<<dim3(8, 21), 256, 0, stream>>>(pyrf, up_w, up_b, pyru, 1344, 512, 64);
  ln_concat<<<5440, 256, 0, stream>>>(e, pyru, norm_g, norm_b, seq, seq_bf);

  // ---- layers ----
  for (int l = 0; l < 4; l++) {
    gemm_bf16<<<dim3(12, 43), 256, 0, stream>>>(seq_bf, qkvw + (size_t)l * 786432,
                                                nullptr, qkv_bf, 1536, 512, 0, 1);
    attn_sparse<<<5440, 512, 0, stream>>>(qkv_bf, o_bf);
    gemm_bf16<<<dim3(4, 43), 256, 0, stream>>>(o_bf, fcw + (size_t)l * 262144,
                                               fc_b + l * 512, t1, 512, 512, 0, 0);
    ln_add<<<5440, 256, 0, stream>>>(seq, t1, ln1_g + l * 512, ln1_b + l * 512, seq_bf);
    gemm_bf16<<<dim3(16, 43), 256, 0, stream>>>(seq_bf, w1t + (size_t)l * 1048576,
                                                b1 + l * 2048, th_bf, 2048, 512, 1, 1);
    gemm_bf16<<<dim3(4, 43), 256, 0, stream>>>(th_bf, w2t + (size_t)l * 1048576,
                                               b2 + l * 512, t1, 512, 2048, 0, 0);
    ln_add<<<5440, 256, 0, stream>>>(seq, t1, ln2_g + l * 512, ln2_b + l * 512, seq_bf);
  }
  gather_out<<<4096, 512, 0, stream>>>(seq, (float*)d_out);
}

// Round 3
// 759.544 us; speedup vs baseline: 3.4807x; 1.1319x over previous
//
#include <hip/hip_runtime.h>
#include <hip/hip_bf16.h>
#include <math.h>

// ---------------------------------------------------------------------------
// B=4, L_IN=1024, D=512, H=8, DK=64, DFF=2048, NL=4, WINDOW=[4,4,4], INNER=5.
// all_size=[1024,256,64,16], L_tot=1360, rows M=5440 padded to M_PAD=5504.
// ---------------------------------------------------------------------------

typedef __attribute__((ext_vector_type(8))) short short8;
typedef __attribute__((ext_vector_type(4))) float f32x4;

__device__ inline ushort f2bf(float x) {
  union { __hip_bfloat16 h; ushort u; } cv; cv.h = __float2bfloat16(x); return cv.u;
}
__device__ inline float bf2f(ushort u) {
  union { unsigned int i; float f; } cv; cv.i = (unsigned)u << 16; return cv.f;
}
__device__ inline float lo16(unsigned u) { union { unsigned i; float f; } c; c.i = u << 16; return c.f; }
__device__ inline float hi16(unsigned u) { union { unsigned i; float f; } c; c.i = u & 0xffff0000u; return c.f; }

#define GLD16(gp, lp)                                                        \
  __builtin_amdgcn_global_load_lds(                                          \
      (const __attribute__((address_space(1))) void*)(gp),                   \
      (__attribute__((address_space(3))) void*)(lp), 16, 0, 0)

// ---------------- embed: circular conv3 + posenc + mark projection ---------
__global__ __launch_bounds__(512) void embed_kernel(
    const float* __restrict__ x_enc, const float* __restrict__ x_mark,
    const float* __restrict__ conv_w, const float* __restrict__ conv_b,
    const float* __restrict__ temp_w, const float* __restrict__ temp_b,
    float* __restrict__ e) {
  int bl = blockIdx.x;
  int b = bl >> 10, l = bl & 1023;
  int d = threadIdx.x;
  int lm1 = (l + 1023) & 1023;
  int lp1 = (l + 1) & 1023;
  const float* w  = conv_w + d * 21;
  const float* x0 = x_enc + (size_t)(b * 1024 + lm1) * 7;
  const float* x1 = x_enc + (size_t)(b * 1024 + l)   * 7;
  const float* x2 = x_enc + (size_t)(b * 1024 + lp1) * 7;
  float acc = conv_b[d];
#pragma unroll
  for (int ci = 0; ci < 7; ci++) {
    acc = fmaf(x0[ci], w[ci * 3 + 0], acc);
    acc = fmaf(x1[ci], w[ci * 3 + 1], acc);
    acc = fmaf(x2[ci], w[ci * 3 + 2], acc);
  }
  int j = d >> 1;
  float dv = expf((float)(2 * j) * (-9.210340371976184f / 512.0f));
  float ang = (float)l * dv;
  float pe = (d & 1) ? cosf(ang) : sinf(ang);
  const float* xm = x_mark + (size_t)(b * 1024 + l) * 4;
  float mk = temp_b[d];
  mk = fmaf(xm[0], temp_w[d],        mk);
  mk = fmaf(xm[1], temp_w[512 + d],  mk);
  mk = fmaf(xm[2], temp_w[1024 + d], mk);
  mk = fmaf(xm[3], temp_w[1536 + d], mk);
  e[(size_t)bl * 512 + d] = acc + pe + mk;
}

// ---------------- weight cast+transpose: f32 [K][N] -> bf16 [N][K] ---------
__global__ __launch_bounds__(256) void transpose_cast(
    const float* __restrict__ src, ushort* __restrict__ dst,
    int K, int N, size_t src_lstride, size_t dst_lstride) {
  src += (size_t)blockIdx.z * src_lstride;
  dst += (size_t)blockIdx.z * dst_lstride;
  __shared__ float t[32][33];
  int k0 = blockIdx.y * 32, n0 = blockIdx.x * 32;
  int tx = threadIdx.x, ty = threadIdx.y;  // (32,8)
#pragma unroll
  for (int i = 0; i < 4; i++)
    t[ty + i * 8][tx] = src[(size_t)(k0 + ty + i * 8) * N + n0 + tx];
  __syncthreads();
#pragma unroll
  for (int i = 0; i < 4; i++)
    dst[(size_t)(n0 + ty + i * 8) * K + k0 + tx] = f2bf(t[tx][ty + i * 8]);
}

// ---------------- bf16 MFMA GEMM, 128x128 tile (m97 structure) -------------
// A: [M_pad][K] bf16.  Bt: [N][K] bf16 (pre-transposed).  act 1 = exact GELU.
__global__ __launch_bounds__(256) void gemm_bf16(
    const ushort* __restrict__ A, const ushort* __restrict__ Bt,
    const float* __restrict__ bias, void* __restrict__ C,
    int N, int K, int act, int out_bf16) {
  __shared__ short As[4096];   // 128 x 32
  __shared__ short Bs[4096];
  int tid = threadIdx.x;
  int w = tid >> 6, lane = tid & 63;
  int bm = blockIdx.y << 7, bn = blockIdx.x << 7;
  const short* Ab = (const short*)A + (size_t)(bm + (tid >> 2)) * K + (tid & 3) * 8;
  const short* Bb = (const short*)Bt + (size_t)(bn + (tid >> 2)) * K + (tid & 3) * 8;
  int ldsw = (tid & 192) * 8;          // wave-uniform: w*512 shorts
  int wr = (w >> 1) << 6, wc = (w & 1) << 6;
  int lr = lane & 15, kg = lane >> 4;
  f32x4 acc[4][4] = {};
  for (int kt = 0; kt < K; kt += 32) {
    GLD16(Ab + kt,                    &As[ldsw]);
    GLD16(Ab + kt + (size_t)64 * K,   &As[2048 + ldsw]);
    GLD16(Bb + kt,                    &Bs[ldsw]);
    GLD16(Bb + kt + (size_t)64 * K,   &Bs[2048 + ldsw]);
    __syncthreads();
    short8 a_[4], b_[4];
#pragma unroll
    for (int m = 0; m < 4; m++)
      a_[m] = *(const short8*)&As[(wr + m * 16 + lr) * 32 + kg * 8];
#pragma unroll
    for (int n = 0; n < 4; n++)
      b_[n] = *(const short8*)&Bs[(wc + n * 16 + lr) * 32 + kg * 8];
#pragma unroll
    for (int m = 0; m < 4; m++)
#pragma unroll
      for (int n = 0; n < 4; n++)
        acc[m][n] = __builtin_amdgcn_mfma_f32_16x16x32_bf16(a_[m], b_[n], acc[m][n], 0, 0, 0);
    __syncthreads();
  }
  int r0 = bm + wr + kg * 4;
  int c0 = bn + wc + lr;
#pragma unroll
  for (int m = 0; m < 4; m++) {
#pragma unroll
    for (int n = 0; n < 4; n++) {
      int col = c0 + n * 16;
      float bv = bias ? bias[col] : 0.0f;
#pragma unroll
      for (int j = 0; j < 4; j++) {
        int row = r0 + m * 16 + j;
        float v = acc[m][n][j] + bv;
        if (act == 1) v = 0.5f * v * (1.0f + erff(v * 0.7071067811865475f));
        if (out_bf16) ((ushort*)C)[(size_t)row * N + col] = f2bf(v);
        else          ((float*)C)[(size_t)row * N + col] = v;
      }
    }
  }
}

// ---------------- bf16 MFMA GEMM, 64x64 tile (high-occupancy, small N) -----
// Same structure, 4 waves each owning a 32x32 quadrant; 1 GLD16 per operand
// per K-step. Grid (N/64, M/64): for N=512 -> 688 blocks (vs 172 at 128^2).
__global__ __launch_bounds__(256) void gemm_bf16_t64(
    const ushort* __restrict__ A, const ushort* __restrict__ Bt,
    const float* __restrict__ bias, void* __restrict__ C,
    int N, int K, int out_bf16) {
  __shared__ short As[2048];   // 64 x 32
  __shared__ short Bs[2048];
  int tid = threadIdx.x;
  int w = tid >> 6, lane = tid & 63;
  int bm = blockIdx.y << 6, bn = blockIdx.x << 6;
  const short* Ab = (const short*)A + (size_t)(bm + (tid >> 2)) * K + (tid & 3) * 8;
  const short* Bb = (const short*)Bt + (size_t)(bn + (tid >> 2)) * K + (tid & 3) * 8;
  int ldsw = w * 512;                  // wave-uniform base (shorts)
  int wr = (w >> 1) << 5, wc = (w & 1) << 5;
  int lr = lane & 15, kg = lane >> 4;
  f32x4 acc[2][2] = {};
  for (int kt = 0; kt < K; kt += 32) {
    GLD16(Ab + kt, &As[ldsw]);
    GLD16(Bb + kt, &Bs[ldsw]);
    __syncthreads();
    short8 a_[2], b_[2];
#pragma unroll
    for (int m = 0; m < 2; m++)
      a_[m] = *(const short8*)&As[(wr + m * 16 + lr) * 32 + kg * 8];
#pragma unroll
    for (int n = 0; n < 2; n++)
      b_[n] = *(const short8*)&Bs[(wc + n * 16 + lr) * 32 + kg * 8];
#pragma unroll
    for (int m = 0; m < 2; m++)
#pragma unroll
      for (int n = 0; n < 2; n++)
        acc[m][n] = __builtin_amdgcn_mfma_f32_16x16x32_bf16(a_[m], b_[n], acc[m][n], 0, 0, 0);
    __syncthreads();
  }
  int r0 = bm + wr + kg * 4;
  int c0 = bn + wc + lr;
#pragma unroll
  for (int m = 0; m < 2; m++) {
#pragma unroll
    for (int n = 0; n < 2; n++) {
      int col = c0 + n * 16;
      float bv = bias ? bias[col] : 0.0f;
#pragma unroll
      for (int j = 0; j < 4; j++) {
        int row = r0 + m * 16 + j;
        float v = acc[m][n][j] + bv;
        if (out_bf16) ((ushort*)C)[(size_t)row * N + col] = f2bf(v);
        else          ((float*)C)[(size_t)row * N + col] = v;
      }
    }
  }
}

// ---------------- small f32 GEMM (down / up projections) -------------------
__global__ __launch_bounds__(256) void gemm_f32(
    const float* __restrict__ A, const float* __restrict__ B,
    const float* __restrict__ bias, float* __restrict__ C,
    int M, int N, int K) {
  __shared__ float As[16][68];
  __shared__ float Bs[16][64];
  int tid = threadIdx.x;
  int tx = tid & 15, ty = tid >> 4;
  int bm = blockIdx.y << 6, bn = blockIdx.x << 6;
  const float* Ab = A + (size_t)bm * K;
  const float* Bb = B + bn;
  float acc[4][4] = {};
  for (int kt = 0; kt < K; kt += 16) {
#pragma unroll
    for (int r = 0; r < 4; r++) {
      int e2 = r * 256 + tid;
      As[e2 & 15][e2 >> 4] = Ab[(size_t)(e2 >> 4) * K + kt + (e2 & 15)];
    }
#pragma unroll
    for (int r = 0; r < 4; r++) {
      int e2 = r * 256 + tid;
      Bs[e2 >> 6][e2 & 63] = Bb[(size_t)(kt + (e2 >> 6)) * N + (e2 & 63)];
    }
    __syncthreads();
#pragma unroll
    for (int kk = 0; kk < 16; kk++) {
      float a0 = As[kk][(ty << 2) + 0], a1 = As[kk][(ty << 2) + 1];
      float a2 = As[kk][(ty << 2) + 2], a3 = As[kk][(ty << 2) + 3];
      float b0 = Bs[kk][(tx << 2) + 0], b1 = Bs[kk][(tx << 2) + 1];
      float b2 = Bs[kk][(tx << 2) + 2], b3 = Bs[kk][(tx << 2) + 3];
      acc[0][0] = fmaf(a0, b0, acc[0][0]); acc[0][1] = fmaf(a0, b1, acc[0][1]);
      acc[0][2] = fmaf(a0, b2, acc[0][2]); acc[0][3] = fmaf(a0, b3, acc[0][3]);
      acc[1][0] = fmaf(a1, b0, acc[1][0]); acc[1][1] = fmaf(a1, b1, acc[1][1]);
      acc[1][2] = fmaf(a1, b2, acc[1][2]); acc[1][3] = fmaf(a1, b3, acc[1][3]);
      acc[2][0] = fmaf(a2, b0, acc[2][0]); acc[2][1] = fmaf(a2, b1, acc[2][1]);
      acc[2][2] = fmaf(a2, b2, acc[2][2]); acc[2][3] = fmaf(a2, b3, acc[2][3]);
      acc[3][0] = fmaf(a3, b0, acc[3][0]); acc[3][1] = fmaf(a3, b1, acc[3][1]);
      acc[3][2] = fmaf(a3, b2, acc[3][2]); acc[3][3] = fmaf(a3, b3, acc[3][3]);
    }
    __syncthreads();
  }
#pragma unroll
  for (int i2 = 0; i2 < 4; i2++) {
    int row = bm + (ty << 2) + i2;
#pragma unroll
    for (int j2 = 0; j2 < 4; j2++) {
      int col = bn + (tx << 2) + j2;
      C[(size_t)row * N + col] = acc[i2][j2] + (bias ? bias[col] : 0.0f);
    }
  }
}

// ---------------- pyramid conv level ---------------------------------------
__global__ __launch_bounds__(64) void pyr_conv(
    const float* __restrict__ in, int in_base, int in_bstr,
    float* __restrict__ out, int out_base, int out_bstr, int out_len,
    const float* __restrict__ w, const float* __restrict__ bias,
    const float* __restrict__ bng, const float* __restrict__ bnb) {
  int blk = blockIdx.x;
  int b = blk / out_len, to = blk - b * out_len;
  int co = threadIdx.x;
  __shared__ float xin[4][64];
  const float* src = in + (size_t)(b * in_bstr + in_base + 4 * to) * 64;
#pragma unroll
  for (int r2 = 0; r2 < 4; r2++) xin[r2][co] = src[r2 * 64 + co];
  __syncthreads();
  const float* wr = w + (size_t)co * 256;
  float acc = bias[co];
#pragma unroll 16
  for (int ci = 0; ci < 64; ci++) {
    acc = fmaf(xin[0][ci], wr[ci * 4 + 0], acc);
    acc = fmaf(xin[1][ci], wr[ci * 4 + 1], acc);
    acc = fmaf(xin[2][ci], wr[ci * 4 + 2], acc);
    acc = fmaf(xin[3][ci], wr[ci * 4 + 3], acc);
  }
  float y = fmaf(bng[co], acc, bnb[co]);
  y = y > 0.0f ? y : expm1f(y);
  out[(size_t)(b * out_bstr + out_base + to) * 64 + co] = y;
}

// ---------------- LayerNorm over concat([embed, pyr_up]); dual output ------
__global__ __launch_bounds__(256) void ln_concat(
    const float* __restrict__ e, const float* __restrict__ pyru,
    const float* __restrict__ g, const float* __restrict__ bta,
    float* __restrict__ seq, ushort* __restrict__ seq_bf) {
  int r = blockIdx.x;
  int b = r / 1360, i = r - b * 1360;
  int tid = threadIdx.x;
  const float* src = (i < 1024)
      ? (e    + (size_t)(b * 1024 + i) * 512)
      : (pyru + (size_t)(b * 336 + (i - 1024)) * 512);
  float v0 = src[tid], v1 = src[tid + 256];
  __shared__ float red[256];
  red[tid] = v0 + v1;
  __syncthreads();
  for (int st = 128; st > 0; st >>= 1) { if (tid < st) red[tid] += red[tid + st]; __syncthreads(); }
  float mu = red[0] * (1.0f / 512.0f);
  __syncthreads();
  float d0 = v0 - mu, d1 = v1 - mu;
  red[tid] = d0 * d0 + d1 * d1;
  __syncthreads();
  for (int st = 128; st > 0; st >>= 1) { if (tid < st) red[tid] += red[tid + st]; __syncthreads(); }
  float inv = rsqrtf(red[0] * (1.0f / 512.0f) + 1e-5f);
  float o0 = d0 * inv * g[tid]       + bta[tid];
  float o1 = d1 * inv * g[tid + 256] + bta[tid + 256];
  float* dst = seq + (size_t)r * 512;
  dst[tid] = o0; dst[tid + 256] = o1;
  ushort* dbf = seq_bf + (size_t)r * 512;
  dbf[tid] = f2bf(o0); dbf[tid + 256] = f2bf(o1);
}

// ---------------- residual add + LayerNorm (in-place), dual output ---------
__global__ __launch_bounds__(256) void ln_add(
    float* __restrict__ seq, const float* __restrict__ t1,
    const float* __restrict__ g, const float* __restrict__ bta,
    ushort* __restrict__ seq_bf) {
  int r = blockIdx.x;
  int tid = threadIdx.x;
  float* row = seq + (size_t)r * 512;
  const float* trow = t1 + (size_t)r * 512;
  float v0 = row[tid] + trow[tid];
  float v1 = row[tid + 256] + trow[tid + 256];
  __shared__ float red[256];
  red[tid] = v0 + v1;
  __syncthreads();
  for (int st = 128; st > 0; st >>= 1) { if (tid < st) red[tid] += red[tid + st]; __syncthreads(); }
  float mu = red[0] * (1.0f / 512.0f);
  __syncthreads();
  float d0 = v0 - mu, d1 = v1 - mu;
  red[tid] = d0 * d0 + d1 * d1;
  __syncthreads();
  for (int st = 128; st > 0; st >>= 1) { if (tid < st) red[tid] += red[tid + st]; __syncthreads(); }
  float inv = rsqrtf(red[0] * (1.0f / 512.0f) + 1e-5f);
  float o0 = d0 * inv * g[tid]       + bta[tid];
  float o1 = d1 * inv * g[tid + 256] + bta[tid + 256];
  row[tid] = o0; row[tid + 256] = o1;
  ushort* dbf = seq_bf + (size_t)r * 512;
  dbf[tid] = f2bf(o0); dbf[tid + 256] = f2bf(o1);
}

// ---------------- sparse pyramidal attention (bf16 qkv in, bf16 o out) -----
__global__ __launch_bounds__(512) void attn_sparse(
    const ushort* __restrict__ qkv, ushort* __restrict__ o) {
  int r = blockIdx.x;
  int b = r / 1360, i = r - b * 1360;
  int h = threadIdx.x >> 6, lane = threadIdx.x & 63;
  __shared__ float sc[8][16];
  __shared__ int keys_s[16];
  __shared__ int nk_s;
  if (threadIdx.x == 0) {
    int S, sz, li;
    if (i < 1024)      { li = 0; S = 0;    sz = 1024; }
    else if (i < 1280) { li = 1; S = 1024; sz = 256; }
    else if (i < 1344) { li = 2; S = 1280; sz = 64; }
    else               { li = 3; S = 1344; sz = 16; }
    int p = i - S;
    int nk = 0;
    int lo = p - 2; if (lo < 0) lo = 0;
    int hi = p + 2; if (hi > sz - 1) hi = sz - 1;
    for (int j2 = lo; j2 <= hi; j2++) keys_s[nk++] = S + j2;
    if (li > 0) {
      int Sprev = (li == 1) ? 0 : (li == 2) ? 1024 : 1280;
      int cb = Sprev + 4 * p;
      keys_s[nk++] = cb; keys_s[nk++] = cb + 1;
      keys_s[nk++] = cb + 2; keys_s[nk++] = cb + 3;
    }
    if (li < 3) {
      int Snext = (li == 0) ? 1024 : (li == 1) ? 1280 : 1344;
      keys_s[nk++] = Snext + (p >> 2);
    }
    nk_s = nk;
  }
  __syncthreads();
  int nk = nk_s;
  if (lane < nk) {
    const uint4* qv = (const uint4*)(qkv + (size_t)r * 1536 + h * 64);
    const uint4* kv = (const uint4*)(qkv + (size_t)(b * 1360 + keys_s[lane]) * 1536 + 512 + h * 64);
    float s = 0.0f;
#pragma unroll
    for (int c = 0; c < 8; c++) {
      uint4 a = qv[c], k4 = kv[c];
      s = fmaf(lo16(a.x), lo16(k4.x), s); s = fmaf(hi16(a.x), hi16(k4.x), s);
      s = fmaf(lo16(a.y), lo16(k4.y), s); s = fmaf(hi16(a.y), hi16(k4.y), s);
      s = fmaf(lo16(a.z), lo16(k4.z), s); s = fmaf(hi16(a.z), hi16(k4.z), s);
      s = fmaf(lo16(a.w), lo16(k4.w), s); s = fmaf(hi16(a.w), hi16(k4.w), s);
    }
    sc[h][lane] = s * 0.125f;
  }
  __syncthreads();
  float m = -1e30f;
  for (int j2 = 0; j2 < nk; j2++) m = fmaxf(m, sc[h][j2]);
  float denom = 0.0f;
  for (int j2 = 0; j2 < nk; j2++) denom += expf(sc[h][j2] - m);
  float inv = 1.0f / denom;
  float acc = 0.0f;
  for (int j2 = 0; j2 < nk; j2++) {
    float pj = expf(sc[h][j2] - m) * inv;
    float vv = bf2f(qkv[(size_t)(b * 1360 + keys_s[j2]) * 1536 + 1024 + h * 64 + lane]);
    acc = fmaf(pj, vv, acc);
  }
  o[(size_t)r * 512 + h * 64 + lane] = f2bf(acc);
}

// ---------------- output gather --------------------------------------------
__global__ __launch_bounds__(512) void gather_out(
    const float* __restrict__ seq, float* __restrict__ out) {
  int bl = blockIdx.x;
  int b = bl >> 10, i = bl & 1023;
  int d = threadIdx.x;
  size_t ob = (size_t)bl * 2048 + d;
  size_t base = (size_t)b * 1360;
  out[ob]        = seq[(base + i) * 512 + d];
  out[ob + 512]  = seq[(base + 1024 + (i >> 2)) * 512 + d];
  out[ob + 1024] = seq[(base + 1280 + (i >> 4)) * 512 + d];
  out[ob + 1536] = seq[(base + 1344 + (i >> 6)) * 512 + d];
}

// ---------------------------------------------------------------------------
extern "C" void kernel_launch(void* const* d_in, const int* in_sizes, int n_in,
                              void* d_out, int out_size, void* d_ws, size_t ws_size,
                              hipStream_t stream) {
  const float* x_enc   = (const float*)d_in[0];
  const float* x_mark  = (const float*)d_in[1];
  const float* conv_w  = (const float*)d_in[2];
  const float* conv_b  = (const float*)d_in[3];
  const float* temp_w  = (const float*)d_in[4];
  const float* temp_b  = (const float*)d_in[5];
  const float* down_w  = (const float*)d_in[6];
  const float* down_b  = (const float*)d_in[7];
  const float* pyr_w   = (const float*)d_in[8];
  const float* pyr_b   = (const float*)d_in[9];
  const float* bn_g    = (const float*)d_in[10];
  const float* bn_b    = (const float*)d_in[11];
  const float* up_w    = (const float*)d_in[12];
  const float* up_b    = (const float*)d_in[13];
  const float* norm_g  = (const float*)d_in[14];
  const float* norm_b  = (const float*)d_in[15];
  const float* wq      = (const float*)d_in[16];
  const float* wk      = (const float*)d_in[17];
  const float* wv      = (const float*)d_in[18];
  const float* fc_w    = (const float*)d_in[19];
  const float* fc_b    = (const float*)d_in[20];
  const float* ln1_g   = (const float*)d_in[21];
  const float* ln1_b   = (const float*)d_in[22];
  const float* w1      = (const float*)d_in[23];
  const float* b1      = (const float*)d_in[24];
  const float* w2      = (const float*)d_in[25];
  const float* b2      = (const float*)d_in[26];
  const float* ln2_g   = (const float*)d_in[27];
  const float* ln2_b   = (const float*)d_in[28];

  // ---- workspace layout (f32-word offsets); total 18,972,672 words = 72.4MB
  float* ws = (float*)d_ws;
  float*  e      = ws;                         // 2,097,152 w
  float*  tmp0   = ws + 2097152;               //   262,144 w
  float*  pyrf   = ws + 2359296;               //    86,016 w
  float*  pyru   = ws + 2445312;               //   688,128 w
  ushort* qkv_bf = (ushort*)ws;                // [5504][1536] bf16
  ushort* o_bf   = (ushort*)(ws + 4227072);    // [5504][512] bf16
  ushort* th_bf  = (ushort*)ws;                // [5504][2048] bf16
  float*  t1     = ws + 5636096;               // [5504][512] f32
  float*  seq    = ws + 8454144;               // [5504][512] f32
  ushort* seq_bf = (ushort*)(ws + 11272192);   // [5504][512] bf16
  ushort* qkvw   = (ushort*)(ws + 12681216);   // 4 x [1536][512] bf16
  ushort* fcw    = (ushort*)(ws + 14254080);   // 4 x [512][512] bf16
  ushort* w1t    = (ushort*)(ws + 14778368);   // 4 x [2048][512] bf16
  ushort* w2t    = (ushort*)(ws + 16875520);   // 4 x [512][2048] bf16

  // ---- weight cast+transpose (once per call) ----
  dim3 tb(32, 8);
  transpose_cast<<<dim3(16, 16, 4), tb, 0, stream>>>(wq, qkvw,          512, 512,  262144, 786432);
  transpose_cast<<<dim3(16, 16, 4), tb, 0, stream>>>(wk, qkvw + 262144, 512, 512,  262144, 786432);
  transpose_cast<<<dim3(16, 16, 4), tb, 0, stream>>>(wv, qkvw + 524288, 512, 512,  262144, 786432);
  transpose_cast<<<dim3(16, 16, 4), tb, 0, stream>>>(fc_w, fcw,         512, 512,  262144, 262144);
  transpose_cast<<<dim3(64, 16, 4), tb, 0, stream>>>(w1, w1t,           512, 2048, 1048576, 1048576);
  transpose_cast<<<dim3(16, 64, 4), tb, 0, stream>>>(w2, w2t,           2048, 512, 1048576, 1048576);

  // ---- prologue ----
  embed_kernel<<<4096, 512, 0, stream>>>(x_enc, x_mark, conv_w, conv_b,
                                         temp_w, temp_b, e);
  gemm_f32<<<dim3(1, 64), 256, 0, stream>>>(e, down_w, down_b, tmp0, 4096, 64, 512);
  pyr_conv<<<4 * 256, 64, 0, stream>>>(tmp0, 0, 1024, pyrf, 0, 336, 256,
                                       pyr_w, pyr_b, bn_g, bn_b);
  pyr_conv<<<4 * 64, 64, 0, stream>>>(pyrf, 0, 336, pyrf, 256, 336, 64,
                                      pyr_w + 16384, pyr_b + 64, bn_g + 64, bn_b + 64);
  pyr_conv<<<4 * 16, 64, 0, stream>>>(pyrf, 256, 336, pyrf, 320, 336, 16,
                                      pyr_w + 32768, pyr_b + 128, bn_g + 128, bn_b + 128);
  gemm_f32<<<dim3(8, 21), 256, 0, stream>>>(pyrf, up_w, up_b, pyru, 1344, 512, 64);
  ln_concat<<<5440, 256, 0, stream>>>(e, pyru, norm_g, norm_b, seq, seq_bf);

  // ---- layers ----
  for (int l = 0; l < 4; l++) {
    gemm_bf16<<<dim3(12, 43), 256, 0, stream>>>(seq_bf, qkvw + (size_t)l * 786432,
                                                nullptr, qkv_bf, 1536, 512, 0, 1);
    attn_sparse<<<5440, 512, 0, stream>>>(qkv_bf, o_bf);
    gemm_bf16_t64<<<dim3(8, 86), 256, 0, stream>>>(o_bf, fcw + (size_t)l * 262144,
                                                   fc_b + l * 512, t1, 512, 512, 0);
    ln_add<<<5440, 256, 0, stream>>>(seq, t1, ln1_g + l * 512, ln1_b + l * 512, seq_bf);
    gemm_bf16<<<dim3(16, 43), 256, 0, stream>>>(seq_bf, w1t + (size_t)l * 1048576,
                                                b1 + l * 2048, th_bf, 2048, 512, 1, 1);
    gemm_bf16_t64<<<dim3(8, 86), 256, 0, stream>>>(th_bf, w2t + (size_t)l * 1048576,
                                                   b2 + l * 512, t1, 512, 2048, 0);
    ln_add<<<5440, 256, 0, stream>>>(seq, t1, ln2_g + l * 512, ln2_b + l * 512, seq_bf);
  }
  gather_out<<<4096, 512, 0, stream>>>(seq, (float*)d_out);
}

// Round 4
// 723.712 us; speedup vs baseline: 3.6531x; 1.0495x over previous
//
#include <hip/hip_runtime.h>
#include <hip/hip_bf16.h>
#include <math.h>

// ---------------------------------------------------------------------------
// B=4, L_IN=1024, D=512, H=8, DK=64, DFF=2048, NL=4, WINDOW=[4,4,4], INNER=5.
// all_size=[1024,256,64,16], L_tot=1360, rows M=5440 padded to M_PAD=5504.
// ---------------------------------------------------------------------------

typedef __attribute__((ext_vector_type(8))) short short8;
typedef __attribute__((ext_vector_type(4))) float f32x4;

__device__ inline ushort f2bf(float x) {
  union { __hip_bfloat16 h; ushort u; } cv; cv.h = __float2bfloat16(x); return cv.u;
}
__device__ inline float bf2f(ushort u) {
  union { unsigned int i; float f; } cv; cv.i = (unsigned)u << 16; return cv.f;
}
__device__ inline float lo16(unsigned u) { union { unsigned i; float f; } c; c.i = u << 16; return c.f; }
__device__ inline float hi16(unsigned u) { union { unsigned i; float f; } c; c.i = u & 0xffff0000u; return c.f; }

// tanh-form GELU (max |err| vs exact erf-GELU ~3e-3; well within budget)
__device__ inline float gelu_f(float x) {
  float y = 0.7978845608028654f * (x + 0.044715f * x * x * x);
  float t = __expf(-2.0f * y);             // e^{-2y}
  float th = (1.0f - t) / (1.0f + t);      // tanh(y)
  return 0.5f * x * (1.0f + th);
}

#define GLD16(gp, lp)                                                        \
  __builtin_amdgcn_global_load_lds(                                          \
      (const __attribute__((address_space(1))) void*)(gp),                   \
      (__attribute__((address_space(3))) void*)(lp), 16, 0, 0)

// ---------------- embed: circular conv3 + posenc + mark projection ---------
__global__ __launch_bounds__(512) void embed_kernel(
    const float* __restrict__ x_enc, const float* __restrict__ x_mark,
    const float* __restrict__ conv_w, const float* __restrict__ conv_b,
    const float* __restrict__ temp_w, const float* __restrict__ temp_b,
    float* __restrict__ e) {
  int bl = blockIdx.x;
  int b = bl >> 10, l = bl & 1023;
  int d = threadIdx.x;
  int lm1 = (l + 1023) & 1023;
  int lp1 = (l + 1) & 1023;
  const float* w  = conv_w + d * 21;
  const float* x0 = x_enc + (size_t)(b * 1024 + lm1) * 7;
  const float* x1 = x_enc + (size_t)(b * 1024 + l)   * 7;
  const float* x2 = x_enc + (size_t)(b * 1024 + lp1) * 7;
  float acc = conv_b[d];
#pragma unroll
  for (int ci = 0; ci < 7; ci++) {
    acc = fmaf(x0[ci], w[ci * 3 + 0], acc);
    acc = fmaf(x1[ci], w[ci * 3 + 1], acc);
    acc = fmaf(x2[ci], w[ci * 3 + 2], acc);
  }
  int j = d >> 1;
  float dv = expf((float)(2 * j) * (-9.210340371976184f / 512.0f));
  float ang = (float)l * dv;
  float pe = (d & 1) ? cosf(ang) : sinf(ang);
  const float* xm = x_mark + (size_t)(b * 1024 + l) * 4;
  float mk = temp_b[d];
  mk = fmaf(xm[0], temp_w[d],        mk);
  mk = fmaf(xm[1], temp_w[512 + d],  mk);
  mk = fmaf(xm[2], temp_w[1024 + d], mk);
  mk = fmaf(xm[3], temp_w[1536 + d], mk);
  e[(size_t)bl * 512 + d] = acc + pe + mk;
}

// ---------------- weight cast+transpose: f32 [K][N] -> bf16 [N][K] ---------
__global__ __launch_bounds__(256) void transpose_cast(
    const float* __restrict__ src, ushort* __restrict__ dst,
    int K, int N, size_t src_lstride, size_t dst_lstride) {
  src += (size_t)blockIdx.z * src_lstride;
  dst += (size_t)blockIdx.z * dst_lstride;
  __shared__ float t[32][33];
  int k0 = blockIdx.y * 32, n0 = blockIdx.x * 32;
  int tx = threadIdx.x, ty = threadIdx.y;  // (32,8)
#pragma unroll
  for (int i = 0; i < 4; i++)
    t[ty + i * 8][tx] = src[(size_t)(k0 + ty + i * 8) * N + n0 + tx];
  __syncthreads();
#pragma unroll
  for (int i = 0; i < 4; i++)
    dst[(size_t)(n0 + ty + i * 8) * K + k0 + tx] = f2bf(t[tx][ty + i * 8]);
}

// ---------------- bf16 MFMA GEMM, 128x128 tile, double-buffered ------------
// A: [M_pad][K] bf16.  Bt: [N][K] bf16 (pre-transposed).  act 1 = GELU.
// Issue tile t+1's global_load_lds BEFORE tile t's compute; one barrier/step.
__global__ __launch_bounds__(256) void gemm_bf16(
    const ushort* __restrict__ A, const ushort* __restrict__ Bt,
    const float* __restrict__ bias, void* __restrict__ C,
    int N, int K, int act, int out_bf16) {
  __shared__ short As[2][4096];   // 2 x (128 x 32)
  __shared__ short Bs[2][4096];
  int tid = threadIdx.x;
  int w = tid >> 6, lane = tid & 63;
  int bm = blockIdx.y << 7, bn = blockIdx.x << 7;
  const short* Ab = (const short*)A + (size_t)(bm + (tid >> 2)) * K + (tid & 3) * 8;
  const short* Bb = (const short*)Bt + (size_t)(bn + (tid >> 2)) * K + (tid & 3) * 8;
  int ldsw = (tid & 192) * 8;          // wave-uniform: w*512 shorts
  int wr = (w >> 1) << 6, wc = (w & 1) << 6;
  int lr = lane & 15, kg = lane >> 4;
  f32x4 acc[4][4] = {};
  // prologue: stage tile 0
  GLD16(Ab,                  &As[0][ldsw]);
  GLD16(Ab + (size_t)64 * K, &As[0][2048 + ldsw]);
  GLD16(Bb,                  &Bs[0][ldsw]);
  GLD16(Bb + (size_t)64 * K, &Bs[0][2048 + ldsw]);
  __syncthreads();
  int nt = K >> 5;
  for (int t = 0; t < nt; t++) {
    int cur = t & 1;
    if (t + 1 < nt) {
      int kt = (t + 1) << 5;
      GLD16(Ab + kt,                  &As[cur ^ 1][ldsw]);
      GLD16(Ab + kt + (size_t)64 * K, &As[cur ^ 1][2048 + ldsw]);
      GLD16(Bb + kt,                  &Bs[cur ^ 1][ldsw]);
      GLD16(Bb + kt + (size_t)64 * K, &Bs[cur ^ 1][2048 + ldsw]);
    }
    short8 a_[4], b_[4];
#pragma unroll
    for (int m = 0; m < 4; m++)
      a_[m] = *(const short8*)&As[cur][(wr + m * 16 + lr) * 32 + kg * 8];
#pragma unroll
    for (int n = 0; n < 4; n++)
      b_[n] = *(const short8*)&Bs[cur][(wc + n * 16 + lr) * 32 + kg * 8];
#pragma unroll
    for (int m = 0; m < 4; m++)
#pragma unroll
      for (int n = 0; n < 4; n++)
        acc[m][n] = __builtin_amdgcn_mfma_f32_16x16x32_bf16(a_[m], b_[n], acc[m][n], 0, 0, 0);
    __syncthreads();
  }
  int r0 = bm + wr + kg * 4;
  int c0 = bn + wc + lr;
#pragma unroll
  for (int m = 0; m < 4; m++) {
#pragma unroll
    for (int n = 0; n < 4; n++) {
      int col = c0 + n * 16;
      float bv = bias ? bias[col] : 0.0f;
#pragma unroll
      for (int j = 0; j < 4; j++) {
        int row = r0 + m * 16 + j;
        float v = acc[m][n][j] + bv;
        if (act == 1) v = gelu_f(v);
        if (out_bf16) ((ushort*)C)[(size_t)row * N + col] = f2bf(v);
        else          ((float*)C)[(size_t)row * N + col] = v;
      }
    }
  }
}

// ---------------- bf16 MFMA GEMM, 64x64 tile, double-buffered --------------
__global__ __launch_bounds__(256) void gemm_bf16_t64(
    const ushort* __restrict__ A, const ushort* __restrict__ Bt,
    const float* __restrict__ bias, void* __restrict__ C,
    int N, int K, int out_bf16) {
  __shared__ short As[2][2048];   // 2 x (64 x 32)
  __shared__ short Bs[2][2048];
  int tid = threadIdx.x;
  int w = tid >> 6, lane = tid & 63;
  int bm = blockIdx.y << 6, bn = blockIdx.x << 6;
  const short* Ab = (const short*)A + (size_t)(bm + (tid >> 2)) * K + (tid & 3) * 8;
  const short* Bb = (const short*)Bt + (size_t)(bn + (tid >> 2)) * K + (tid & 3) * 8;
  int ldsw = w * 512;                  // wave-uniform base (shorts)
  int wr = (w >> 1) << 5, wc = (w & 1) << 5;
  int lr = lane & 15, kg = lane >> 4;
  f32x4 acc[2][2] = {};
  GLD16(Ab, &As[0][ldsw]);
  GLD16(Bb, &Bs[0][ldsw]);
  __syncthreads();
  int nt = K >> 5;
  for (int t = 0; t < nt; t++) {
    int cur = t & 1;
    if (t + 1 < nt) {
      int kt = (t + 1) << 5;
      GLD16(Ab + kt, &As[cur ^ 1][ldsw]);
      GLD16(Bb + kt, &Bs[cur ^ 1][ldsw]);
    }
    short8 a_[2], b_[2];
#pragma unroll
    for (int m = 0; m < 2; m++)
      a_[m] = *(const short8*)&As[cur][(wr + m * 16 + lr) * 32 + kg * 8];
#pragma unroll
    for (int n = 0; n < 2; n++)
      b_[n] = *(const short8*)&Bs[cur][(wc + n * 16 + lr) * 32 + kg * 8];
#pragma unroll
    for (int m = 0; m < 2; m++)
#pragma unroll
      for (int n = 0; n < 2; n++)
        acc[m][n] = __builtin_amdgcn_mfma_f32_16x16x32_bf16(a_[m], b_[n], acc[m][n], 0, 0, 0);
    __syncthreads();
  }
  int r0 = bm + wr + kg * 4;
  int c0 = bn + wc + lr;
#pragma unroll
  for (int m = 0; m < 2; m++) {
#pragma unroll
    for (int n = 0; n < 2; n++) {
      int col = c0 + n * 16;
      float bv = bias ? bias[col] : 0.0f;
#pragma unroll
      for (int j = 0; j < 4; j++) {
        int row = r0 + m * 16 + j;
        float v = acc[m][n][j] + bv;
        if (out_bf16) ((ushort*)C)[(size_t)row * N + col] = f2bf(v);
        else          ((float*)C)[(size_t)row * N + col] = v;
      }
    }
  }
}

// ---------------- small f32 GEMM (down / up projections) -------------------
__global__ __launch_bounds__(256) void gemm_f32(
    const float* __restrict__ A, const float* __restrict__ B,
    const float* __restrict__ bias, float* __restrict__ C,
    int M, int N, int K) {
  __shared__ float As[16][68];
  __shared__ float Bs[16][64];
  int tid = threadIdx.x;
  int tx = tid & 15, ty = tid >> 4;
  int bm = blockIdx.y << 6, bn = blockIdx.x << 6;
  const float* Ab = A + (size_t)bm * K;
  const float* Bb = B + bn;
  float acc[4][4] = {};
  for (int kt = 0; kt < K; kt += 16) {
#pragma unroll
    for (int r = 0; r < 4; r++) {
      int e2 = r * 256 + tid;
      As[e2 & 15][e2 >> 4] = Ab[(size_t)(e2 >> 4) * K + kt + (e2 & 15)];
    }
#pragma unroll
    for (int r = 0; r < 4; r++) {
      int e2 = r * 256 + tid;
      Bs[e2 >> 6][e2 & 63] = Bb[(size_t)(kt + (e2 >> 6)) * N + (e2 & 63)];
    }
    __syncthreads();
#pragma unroll
    for (int kk = 0; kk < 16; kk++) {
      float a0 = As[kk][(ty << 2) + 0], a1 = As[kk][(ty << 2) + 1];
      float a2 = As[kk][(ty << 2) + 2], a3 = As[kk][(ty << 2) + 3];
      float b0 = Bs[kk][(tx << 2) + 0], b1 = Bs[kk][(tx << 2) + 1];
      float b2 = Bs[kk][(tx << 2) + 2], b3 = Bs[kk][(tx << 2) + 3];
      acc[0][0] = fmaf(a0, b0, acc[0][0]); acc[0][1] = fmaf(a0, b1, acc[0][1]);
      acc[0][2] = fmaf(a0, b2, acc[0][2]); acc[0][3] = fmaf(a0, b3, acc[0][3]);
      acc[1][0] = fmaf(a1, b0, acc[1][0]); acc[1][1] = fmaf(a1, b1, acc[1][1]);
      acc[1][2] = fmaf(a1, b2, acc[1][2]); acc[1][3] = fmaf(a1, b3, acc[1][3]);
      acc[2][0] = fmaf(a2, b0, acc[2][0]); acc[2][1] = fmaf(a2, b1, acc[2][1]);
      acc[2][2] = fmaf(a2, b2, acc[2][2]); acc[2][3] = fmaf(a2, b3, acc[2][3]);
      acc[3][0] = fmaf(a3, b0, acc[3][0]); acc[3][1] = fmaf(a3, b1, acc[3][1]);
      acc[3][2] = fmaf(a3, b2, acc[3][2]); acc[3][3] = fmaf(a3, b3, acc[3][3]);
    }
    __syncthreads();
  }
#pragma unroll
  for (int i2 = 0; i2 < 4; i2++) {
    int row = bm + (ty << 2) + i2;
#pragma unroll
    for (int j2 = 0; j2 < 4; j2++) {
      int col = bn + (tx << 2) + j2;
      C[(size_t)row * N + col] = acc[i2][j2] + (bias ? bias[col] : 0.0f);
    }
  }
}

// ---------------- pyramid conv level ---------------------------------------
__global__ __launch_bounds__(64) void pyr_conv(
    const float* __restrict__ in, int in_base, int in_bstr,
    float* __restrict__ out, int out_base, int out_bstr, int out_len,
    const float* __restrict__ w, const float* __restrict__ bias,
    const float* __restrict__ bng, const float* __restrict__ bnb) {
  int blk = blockIdx.x;
  int b = blk / out_len, to = blk - b * out_len;
  int co = threadIdx.x;
  __shared__ float xin[4][64];
  const float* src = in + (size_t)(b * in_bstr + in_base + 4 * to) * 64;
#pragma unroll
  for (int r2 = 0; r2 < 4; r2++) xin[r2][co] = src[r2 * 64 + co];
  __syncthreads();
  const float* wr = w + (size_t)co * 256;
  float acc = bias[co];
#pragma unroll 16
  for (int ci = 0; ci < 64; ci++) {
    acc = fmaf(xin[0][ci], wr[ci * 4 + 0], acc);
    acc = fmaf(xin[1][ci], wr[ci * 4 + 1], acc);
    acc = fmaf(xin[2][ci], wr[ci * 4 + 2], acc);
    acc = fmaf(xin[3][ci], wr[ci * 4 + 3], acc);
  }
  float y = fmaf(bng[co], acc, bnb[co]);
  y = y > 0.0f ? y : expm1f(y);
  out[(size_t)(b * out_bstr + out_base + to) * 64 + co] = y;
}

// ---------------- LayerNorm over concat([embed, pyr_up]); dual output ------
__global__ __launch_bounds__(256) void ln_concat(
    const float* __restrict__ e, const float* __restrict__ pyru,
    const float* __restrict__ g, const float* __restrict__ bta,
    float* __restrict__ seq, ushort* __restrict__ seq_bf) {
  int r = blockIdx.x;
  int b = r / 1360, i = r - b * 1360;
  int tid = threadIdx.x;
  const float* src = (i < 1024)
      ? (e    + (size_t)(b * 1024 + i) * 512)
      : (pyru + (size_t)(b * 336 + (i - 1024)) * 512);
  float v0 = src[tid], v1 = src[tid + 256];
  __shared__ float red[256];
  red[tid] = v0 + v1;
  __syncthreads();
  for (int st = 128; st > 0; st >>= 1) { if (tid < st) red[tid] += red[tid + st]; __syncthreads(); }
  float mu = red[0] * (1.0f / 512.0f);
  __syncthreads();
  float d0 = v0 - mu, d1 = v1 - mu;
  red[tid] = d0 * d0 + d1 * d1;
  __syncthreads();
  for (int st = 128; st > 0; st >>= 1) { if (tid < st) red[tid] += red[tid + st]; __syncthreads(); }
  float inv = rsqrtf(red[0] * (1.0f / 512.0f) + 1e-5f);
  float o0 = d0 * inv * g[tid]       + bta[tid];
  float o1 = d1 * inv * g[tid + 256] + bta[tid + 256];
  float* dst = seq + (size_t)r * 512;
  dst[tid] = o0; dst[tid + 256] = o1;
  ushort* dbf = seq_bf + (size_t)r * 512;
  dbf[tid] = f2bf(o0); dbf[tid + 256] = f2bf(o1);
}

// ---------------- residual add + LayerNorm (in-place), dual output ---------
__global__ __launch_bounds__(256) void ln_add(
    float* __restrict__ seq, const float* __restrict__ t1,
    const float* __restrict__ g, const float* __restrict__ bta,
    ushort* __restrict__ seq_bf) {
  int r = blockIdx.x;
  int tid = threadIdx.x;
  float* row = seq + (size_t)r * 512;
  const float* trow = t1 + (size_t)r * 512;
  float v0 = row[tid] + trow[tid];
  float v1 = row[tid + 256] + trow[tid + 256];
  __shared__ float red[256];
  red[tid] = v0 + v1;
  __syncthreads();
  for (int st = 128; st > 0; st >>= 1) { if (tid < st) red[tid] += red[tid + st]; __syncthreads(); }
  float mu = red[0] * (1.0f / 512.0f);
  __syncthreads();
  float d0 = v0 - mu, d1 = v1 - mu;
  red[tid] = d0 * d0 + d1 * d1;
  __syncthreads();
  for (int st = 128; st > 0; st >>= 1) { if (tid < st) red[tid] += red[tid + st]; __syncthreads(); }
  float inv = rsqrtf(red[0] * (1.0f / 512.0f) + 1e-5f);
  float o0 = d0 * inv * g[tid]       + bta[tid];
  float o1 = d1 * inv * g[tid + 256] + bta[tid + 256];
  row[tid] = o0; row[tid + 256] = o1;
  ushort* dbf = seq_bf + (size_t)r * 512;
  dbf[tid] = f2bf(o0); dbf[tid + 256] = f2bf(o1);
}

// ---------------- sparse pyramidal attention (bf16 qkv in, bf16 o out) -----
__global__ __launch_bounds__(512) void attn_sparse(
    const ushort* __restrict__ qkv, ushort* __restrict__ o) {
  int r = blockIdx.x;
  int b = r / 1360, i = r - b * 1360;
  int h = threadIdx.x >> 6, lane = threadIdx.x & 63;
  __shared__ float sc[8][16];
  __shared__ int keys_s[16];
  __shared__ int nk_s;
  if (threadIdx.x == 0) {
    int S, sz, li;
    if (i < 1024)      { li = 0; S = 0;    sz = 1024; }
    else if (i < 1280) { li = 1; S = 1024; sz = 256; }
    else if (i < 1344) { li = 2; S = 1280; sz = 64; }
    else               { li = 3; S = 1344; sz = 16; }
    int p = i - S;
    int nk = 0;
    int lo = p - 2; if (lo < 0) lo = 0;
    int hi = p + 2; if (hi > sz - 1) hi = sz - 1;
    for (int j2 = lo; j2 <= hi; j2++) keys_s[nk++] = S + j2;
    if (li > 0) {
      int Sprev = (li == 1) ? 0 : (li == 2) ? 1024 : 1280;
      int cb = Sprev + 4 * p;
      keys_s[nk++] = cb; keys_s[nk++] = cb + 1;
      keys_s[nk++] = cb + 2; keys_s[nk++] = cb + 3;
    }
    if (li < 3) {
      int Snext = (li == 0) ? 1024 : (li == 1) ? 1280 : 1344;
      keys_s[nk++] = Snext + (p >> 2);
    }
    nk_s = nk;
  }
  __syncthreads();
  int nk = nk_s;
  if (lane < nk) {
    const uint4* qv = (const uint4*)(qkv + (size_t)r * 1536 + h * 64);
    const uint4* kv = (const uint4*)(qkv + (size_t)(b * 1360 + keys_s[lane]) * 1536 + 512 + h * 64);
    float s = 0.0f;
#pragma unroll
    for (int c = 0; c < 8; c++) {
      uint4 a = qv[c], k4 = kv[c];
      s = fmaf(lo16(a.x), lo16(k4.x), s); s = fmaf(hi16(a.x), hi16(k4.x), s);
      s = fmaf(lo16(a.y), lo16(k4.y), s); s = fmaf(hi16(a.y), hi16(k4.y), s);
      s = fmaf(lo16(a.z), lo16(k4.z), s); s = fmaf(hi16(a.z), hi16(k4.z), s);
      s = fmaf(lo16(a.w), lo16(k4.w), s); s = fmaf(hi16(a.w), hi16(k4.w), s);
    }
    sc[h][lane] = s * 0.125f;
  }
  __syncthreads();
  float m = -1e30f;
  for (int j2 = 0; j2 < nk; j2++) m = fmaxf(m, sc[h][j2]);
  float denom = 0.0f;
  for (int j2 = 0; j2 < nk; j2++) denom += expf(sc[h][j2] - m);
  float inv = 1.0f / denom;
  float acc = 0.0f;
  for (int j2 = 0; j2 < nk; j2++) {
    float pj = expf(sc[h][j2] - m) * inv;
    float vv = bf2f(qkv[(size_t)(b * 1360 + keys_s[j2]) * 1536 + 1024 + h * 64 + lane]);
    acc = fmaf(pj, vv, acc);
  }
  o[(size_t)r * 512 + h * 64 + lane] = f2bf(acc);
}

// ---------------- output gather --------------------------------------------
__global__ __launch_bounds__(512) void gather_out(
    const float* __restrict__ seq, float* __restrict__ out) {
  int bl = blockIdx.x;
  int b = bl >> 10, i = bl & 1023;
  int d = threadIdx.x;
  size_t ob = (size_t)bl * 2048 + d;
  size_t base = (size_t)b * 1360;
  out[ob]        = seq[(base + i) * 512 + d];
  out[ob + 512]  = seq[(base + 1024 + (i >> 2)) * 512 + d];
  out[ob + 1024] = seq[(base + 1280 + (i >> 4)) * 512 + d];
  out[ob + 1536] = seq[(base + 1344 + (i >> 6)) * 512 + d];
}

// ---------------------------------------------------------------------------
extern "C" void kernel_launch(void* const* d_in, const int* in_sizes, int n_in,
                              void* d_out, int out_size, void* d_ws, size_t ws_size,
                              hipStream_t stream) {
  const float* x_enc   = (const float*)d_in[0];
  const float* x_mark  = (const float*)d_in[1];
  const float* conv_w  = (const float*)d_in[2];
  const float* conv_b  = (const float*)d_in[3];
  const float* temp_w  = (const float*)d_in[4];
  const float* temp_b  = (const float*)d_in[5];
  const float* down_w  = (const float*)d_in[6];
  const float* down_b  = (const float*)d_in[7];
  const float* pyr_w   = (const float*)d_in[8];
  const float* pyr_b   = (const float*)d_in[9];
  const float* bn_g    = (const float*)d_in[10];
  const float* bn_b    = (const float*)d_in[11];
  const float* up_w    = (const float*)d_in[12];
  const float* up_b    = (const float*)d_in[13];
  const float* norm_g  = (const float*)d_in[14];
  const float* norm_b  = (const float*)d_in[15];
  const float* wq      = (const float*)d_in[16];
  const float* wk      = (const float*)d_in[17];
  const float* wv      = (const float*)d_in[18];
  const float* fc_w    = (const float*)d_in[19];
  const float* fc_b    = (const float*)d_in[20];
  const float* ln1_g   = (const float*)d_in[21];
  const float* ln1_b   = (const float*)d_in[22];
  const float* w1      = (const float*)d_in[23];
  const float* b1      = (const float*)d_in[24];
  const float* w2      = (const float*)d_in[25];
  const float* b2      = (const float*)d_in[26];
  const float* ln2_g   = (const float*)d_in[27];
  const float* ln2_b   = (const float*)d_in[28];

  // ---- workspace layout (f32-word offsets); total 18,972,672 words = 72.4MB
  float* ws = (float*)d_ws;
  float*  e      = ws;                         // 2,097,152 w
  float*  tmp0   = ws + 2097152;               //   262,144 w
  float*  pyrf   = ws + 2359296;               //    86,016 w
  float*  pyru   = ws + 2445312;               //   688,128 w
  ushort* qkv_bf = (ushort*)ws;                // [5504][1536] bf16
  ushort* o_bf   = (ushort*)(ws + 4227072);    // [5504][512] bf16
  ushort* th_bf  = (ushort*)ws;                // [5504][2048] bf16
  float*  t1     = ws + 5636096;               // [5504][512] f32
  float*  seq    = ws + 8454144;               // [5504][512] f32
  ushort* seq_bf = (ushort*)(ws + 11272192);   // [5504][512] bf16
  ushort* qkvw   = (ushort*)(ws + 12681216);   // 4 x [1536][512] bf16
  ushort* fcw    = (ushort*)(ws + 14254080);   // 4 x [512][512] bf16
  ushort* w1t    = (ushort*)(ws + 14778368);   // 4 x [2048][512] bf16
  ushort* w2t    = (ushort*)(ws + 16875520);   // 4 x [512][2048] bf16

  // ---- weight cast+transpose (once per call) ----
  dim3 tb(32, 8);
  transpose_cast<<<dim3(16, 16, 4), tb, 0, stream>>>(wq, qkvw,          512, 512,  262144, 786432);
  transpose_cast<<<dim3(16, 16, 4), tb, 0, stream>>>(wk, qkvw + 262144, 512, 512,  262144, 786432);
  transpose_cast<<<dim3(16, 16, 4), tb, 0, stream>>>(wv, qkvw + 524288, 512, 512,  262144, 786432);
  transpose_cast<<<dim3(16, 16, 4), tb, 0, stream>>>(fc_w, fcw,         512, 512,  262144, 262144);
  transpose_cast<<<dim3(64, 16, 4), tb, 0, stream>>>(w1, w1t,           512, 2048, 1048576, 1048576);
  transpose_cast<<<dim3(16, 64, 4), tb, 0, stream>>>(w2, w2t,           2048, 512, 1048576, 1048576);

  // ---- prologue ----
  embed_kernel<<<4096, 512, 0, stream>>>(x_enc, x_mark, conv_w, conv_b,
                                         temp_w, temp_b, e);
  gemm_f32<<<dim3(1, 64), 256, 0, stream>>>(e, down_w, down_b, tmp0, 4096, 64, 512);
  pyr_conv<<<4 * 256, 64, 0, stream>>>(tmp0, 0, 1024, pyrf, 0, 336, 256,
                                       pyr_w, pyr_b, bn_g, bn_b);
  pyr_conv<<<4 * 64, 64, 0, stream>>>(pyrf, 0, 336, pyrf, 256, 336, 64,
                                      pyr_w + 16384, pyr_b + 64, bn_g + 64, bn_b + 64);
  pyr_conv<<<4 * 16, 64, 0, stream>>>(pyrf, 256, 336, pyrf, 320, 336, 16,
                                      pyr_w + 32768, pyr_b + 128, bn_g + 128, bn_b + 128);
  gemm_f32<<<dim3(8, 21), 256, 0, stream>>>(pyrf, up_w, up_b, pyru, 1344, 512, 64);
  ln_concat<<<5440, 256, 0, stream>>>(e, pyru, norm_g, norm_b, seq, seq_bf);

  // ---- layers ----
  for (int l = 0; l < 4; l++) {
    gemm_bf16<<<dim3(12, 43), 256, 0, stream>>>(seq_bf, qkvw + (size_t)l * 786432,
                                                nullptr, qkv_bf, 1536, 512, 0, 1);
    attn_sparse<<<5440, 512, 0, stream>>>(qkv_bf, o_bf);
    gemm_bf16_t64<<<dim3(8, 86), 256, 0, stream>>>(o_bf, fcw + (size_t)l * 262144,
                                                   fc_b + l * 512, t1, 512, 512, 0);
    ln_add<<<5440, 256, 0, stream>>>(seq, t1, ln1_g + l * 512, ln1_b + l * 512, seq_bf);
    gemm_bf16<<<dim3(16, 43), 256, 0, stream>>>(seq_bf, w1t + (size_t)l * 1048576,
                                                b1 + l * 2048, th_bf, 2048, 512, 1, 1);
    gemm_bf16_t64<<<dim3(8, 86), 256, 0, stream>>>(th_bf, w2t + (size_t)l * 1048576,
                                                   b2 + l * 512, t1, 512, 2048, 0);
    ln_add<<<5440, 256, 0, stream>>>(seq, t1, ln2_g + l * 512, ln2_b + l * 512, seq_bf);
  }
  gather_out<<<4096, 512, 0, stream>>>(seq, (float*)d_out);
}